// Round 6
// baseline (2764.293 us; speedup 1.0000x reference)
//
#include <hip/hip_runtime.h>
#include <hip/hip_bf16.h>

typedef __attribute__((ext_vector_type(8))) __bf16 bf16x8;
typedef __attribute__((ext_vector_type(4))) float floatx4;

typedef __attribute__((address_space(1))) const unsigned char kGlb;
typedef __attribute__((address_space(3))) unsigned char kLds;

static constexpr int S = 2048;
static constexpr int D = 2048;
static constexpr int HD = 256;
static constexpr int NH = 8;
static constexpr int NKV = 4;
static constexpr int NLAYER = 4;
static constexpr int VOCAB = 32000;
static constexpr int FF = 8192;
static constexpr int WINDOW = 1024;

// ---------------- block reduction helpers (256 threads = 4 waves) ----------------
__device__ __forceinline__ float blk_sum(float v) {
    __shared__ float sm[4];
    #pragma unroll
    for (int o = 32; o > 0; o >>= 1) v += __shfl_down(v, o, 64);
    int lane = threadIdx.x & 63, w = threadIdx.x >> 6;
    __syncthreads();
    if (lane == 0) sm[w] = v;
    __syncthreads();
    return sm[0] + sm[1] + sm[2] + sm[3];
}

__device__ __forceinline__ float blk_max(float v) {
    __shared__ float sm[4];
    #pragma unroll
    for (int o = 32; o > 0; o >>= 1) v = fmaxf(v, __shfl_down(v, o, 64));
    int lane = threadIdx.x & 63, w = threadIdx.x >> 6;
    __syncthreads();
    if (lane == 0) sm[w] = v;
    __syncthreads();
    return fmaxf(fmaxf(sm[0], sm[1]), fmaxf(sm[2], sm[3]));
}

// ---------------- elementwise kernels ----------------
__global__ void embed_kernel(const int* __restrict__ ids, const float* __restrict__ E,
                             float* __restrict__ h) {
    int d = blockIdx.x * 256 + threadIdx.x;
    int s = blockIdx.y;
    h[(long)s * D + d] = E[(long)ids[s] * D + d] * 45.25483399593904f; // sqrt(2048)
}

__global__ void rope_table_kernel(float* __restrict__ c, float* __restrict__ sn) {
    int i = threadIdx.x;   // 0..127
    int p = blockIdx.x;    // 0..S-1
    float inv = powf(10000.f, -(float)i / 128.f);
    float a = (float)p * inv;
    c[p * 128 + i] = cosf(a);
    sn[p * 128 + i] = sinf(a);
}

// fp32 -> bf16 conversion (grid-stride, 8 elems/thread/iter)
__global__ void cvt_bf16_kernel(const float* __restrict__ src, __hip_bfloat16* __restrict__ dst,
                                long n8) {
    long stride = (long)gridDim.x * 256;
    for (long i = (long)blockIdx.x * 256 + threadIdx.x; i < n8; i += stride) {
        long o = i * 8;
        float4 a = *(const float4*)(src + o);
        float4 b = *(const float4*)(src + o + 4);
        __hip_bfloat16 h8[8] = {
            __float2bfloat16(a.x), __float2bfloat16(a.y),
            __float2bfloat16(a.z), __float2bfloat16(a.w),
            __float2bfloat16(b.x), __float2bfloat16(b.y),
            __float2bfloat16(b.z), __float2bfloat16(b.w)};
        *(uint4*)(dst + o) = *(const uint4*)h8;
    }
}

// x = rms(h, w) -> bf16
__global__ void rms_bf16_kernel(const float* __restrict__ h, const float* __restrict__ w,
                                __hip_bfloat16* __restrict__ o) {
    int s = blockIdx.x;
    const float* row = h + (long)s * D;
    float vals[8], ss = 0.f;
    #pragma unroll
    for (int t = 0; t < 8; ++t) {
        int j = t * 256 + threadIdx.x;
        float v = row[j]; vals[t] = v; ss += v * v;
    }
    ss = blk_sum(ss);
    float r = rsqrtf(ss * (1.f / D) + 1e-6f);
    #pragma unroll
    for (int t = 0; t < 8; ++t) {
        int j = t * 256 + threadIdx.x;
        o[(long)s * D + j] = __float2bfloat16(vals[t] * r * (1.f + w[j]));
    }
}

// h += rms(t, w)
__global__ void resid_rms_kernel(float* __restrict__ h, const float* __restrict__ tt,
                                 const float* __restrict__ w) {
    int s = blockIdx.x;
    const float* row = tt + (long)s * D;
    float* hr = h + (long)s * D;
    float vals[8], ss = 0.f;
    #pragma unroll
    for (int t = 0; t < 8; ++t) {
        int j = t * 256 + threadIdx.x;
        float v = row[j]; vals[t] = v; ss += v * v;
    }
    ss = blk_sum(ss);
    float r = rsqrtf(ss * (1.f / D) + 1e-6f);
    #pragma unroll
    for (int t = 0; t < 8; ++t) {
        int j = t * 256 + threadIdx.x;
        hr[j] += vals[t] * r * (1.f + w[j]);
    }
}

// in-place RoPE on rows with stride ldx; head offset hh*HD; 128 threads per (s, head)
__global__ void rope_kernel(__hip_bfloat16* __restrict__ x, const float* __restrict__ cb,
                            const float* __restrict__ sb, int ldx) {
    int s = blockIdx.x, hh = blockIdx.y, i = threadIdx.x; // i in 0..127
    __hip_bfloat16* p = x + (long)s * ldx + hh * HD;
    float x1 = __bfloat162float(p[i]);
    float x2 = __bfloat162float(p[128 + i]);
    float c = cb[s * 128 + i], sn = sb[s * 128 + i];
    p[i]       = __float2bfloat16(x1 * c - x2 * sn);
    p[128 + i] = __float2bfloat16(x1 * sn + x2 * c);
}

// v rows (stride ldv, base already offset to v region) -> vT (NKV, HD, S) bf16
__global__ void transpose_v_kernel(const __hip_bfloat16* __restrict__ v,
                                   __hip_bfloat16* __restrict__ vt, int ldv) {
    __shared__ ushort tile[64][65];
    int s0 = blockIdx.x * 64, d0 = blockIdx.y * 64, kv = blockIdx.z;
    const ushort* vin = (const ushort*)v;
    ushort* vout = (ushort*)vt;
    #pragma unroll
    for (int it = 0; it < 4; ++it) {
        int slot = it * 256 + threadIdx.x;
        int r = slot >> 4, c4 = (slot & 15) << 2;
        ushort4 x = *(const ushort4*)(vin + (long)(s0 + r) * ldv + kv * HD + d0 + c4);
        tile[r][c4] = x.x; tile[r][c4 + 1] = x.y; tile[r][c4 + 2] = x.z; tile[r][c4 + 3] = x.w;
    }
    __syncthreads();
    #pragma unroll
    for (int it = 0; it < 4; ++it) {
        int slot = it * 256 + threadIdx.x;
        int rr = slot >> 4, c4 = (slot & 15) << 2;
        ushort4 y;
        y.x = tile[c4][rr]; y.y = tile[c4 + 1][rr]; y.z = tile[c4 + 2][rr]; y.w = tile[c4 + 3][rr];
        *(ushort4*)(vout + (long)kv * HD * S + (long)(d0 + rr) * S + s0 + c4) = y;
    }
}

// scores (NH,S,S) f32 -> probs bf16, with scale, tanh softcap, mask, softmax.
__global__ void softmax_kernel(const float* __restrict__ sc, __hip_bfloat16* __restrict__ pr,
                               int isLocal) {
    int i = blockIdx.x, hh = blockIdx.y;
    const float* row = sc + ((long)hh * S + i) * S;
    __hip_bfloat16* orow = pr + ((long)hh * S + i) * S;
    int lo = isLocal ? max(0, i - (WINDOW - 1)) : 0;
    float vals[8];
    float m = -3.0e38f;
    #pragma unroll
    for (int t = 0; t < 8; ++t) {
        int j = t * 256 + threadIdx.x;
        bool chunkAny = (t * 256 <= i) && (t * 256 + 255 >= lo);
        if (chunkAny) {
            bool valid = (j <= i) && (j >= lo);
            float v = tanhf(row[j] * (0.0625f / 50.f)) * 50.f; // SCALE=1/16, softcap 50
            vals[t] = valid ? v : -3.0e38f;
            m = fmaxf(m, vals[t]);
        } else {
            vals[t] = -3.0e38f;
        }
    }
    m = blk_max(m);
    float ps[8], ssum = 0.f;
    #pragma unroll
    for (int t = 0; t < 8; ++t) {
        float p = (vals[t] > -1.0e38f) ? __expf(vals[t] - m) : 0.f;
        ps[t] = p; ssum += p;
    }
    ssum = blk_sum(ssum);
    float inv = 1.f / ssum;
    #pragma unroll
    for (int t = 0; t < 8; ++t) {
        int j = t * 256 + threadIdx.x;
        orow[j] = __float2bfloat16(ps[t] * inv);
    }
}

// gate half *= up half, packed gu[S][16384]
__global__ void mul_gu_kernel(__hip_bfloat16* __restrict__ gu) {
    long idx = ((long)blockIdx.x * 256 + threadIdx.x) * 8;
    long s = idx >> 13;
    long f = idx & 8191;
    __hip_bfloat16* gp = gu + s * 16384 + f;
    const __hip_bfloat16* up = gu + s * 16384 + 8192 + f;
    uint4 gv = *(const uint4*)gp;
    uint4 uv = *(const uint4*)up;
    const __hip_bfloat16* gb = (const __hip_bfloat16*)&gv;
    const __hip_bfloat16* ub = (const __hip_bfloat16*)&uv;
    __hip_bfloat16 o[8];
    #pragma unroll
    for (int j = 0; j < 8; ++j)
        o[j] = __float2bfloat16(__bfloat162float(gb[j]) * __bfloat162float(ub[j]));
    *(uint4*)gp = *(const uint4*)o;
}

// ================= 8-phase 256x256 GEMM (m201-style): C = A[M,K] * B[N,K]^T =================
// BK=64, 8 waves (2Mx4N), 2 dbuf x 2 half per operand (128 KiB LDS), half-tile staging
// (one 128x64 half per phase), counted vmcnt(8) (never drains in main loop), quadrant
// phases (qm,qn) = (0,0),(0,1),(1,0),(1,1); B-frags held in regs across phases.
// Swizzle: 16B-chunk c' = c ^ (row&7) within 128B rows, applied on BOTH gload-src and ds_read.
// LDS half layout: row r (0..127) at byte r*128; i-group 1 (rows 64..127) starts at byte 8192.
// EPI: 3 = tanh(x/30)*30 -> f32 (LM head), 4 = gelu if global col<8192 else plain -> bf16
#define RD_AF(BUF, HALF)                                                          \
    {                                                                             \
        const char* _p = (const char*)&ldsA[BUF][HALF][0];                        \
        _Pragma("unroll")                                                         \
        for (int mi = 0; mi < 4; ++mi) {                                          \
            int r = wm * 64 + mi * 16 + fr;                                       \
            _Pragma("unroll")                                                     \
            for (int ks = 0; ks < 2; ++ks) {                                      \
                int c = ks * 4 + g;                                               \
                af[mi][ks] = *(const bf16x8*)(_p + r * 128 + ((c ^ (r & 7)) << 4)); \
            }                                                                     \
        }                                                                         \
    }

#define RD_BF(DST, BUF, HALF)                                                     \
    {                                                                             \
        const char* _p = (const char*)&ldsB[BUF][HALF][0];                        \
        _Pragma("unroll")                                                         \
        for (int ni = 0; ni < 2; ++ni) {                                          \
            int r = wn * 32 + ni * 16 + fr;                                       \
            _Pragma("unroll")                                                     \
            for (int ks = 0; ks < 2; ++ks) {                                      \
                int c = ks * 4 + g;                                               \
                DST[ni][ks] = *(const bf16x8*)(_p + r * 128 + ((c ^ (r & 7)) << 4)); \
            }                                                                     \
        }                                                                         \
    }

#define MM(QM, QN, BF)                                                            \
    __builtin_amdgcn_s_setprio(1);                                                \
    _Pragma("unroll")                                                             \
    for (int mi = 0; mi < 4; ++mi)                                                \
        _Pragma("unroll")                                                         \
        for (int ni = 0; ni < 2; ++ni)                                            \
            _Pragma("unroll")                                                     \
            for (int ks = 0; ks < 2; ++ks)                                        \
                acc[QM][QN][mi][ni] = __builtin_amdgcn_mfma_f32_16x16x32_bf16(    \
                    af[mi][ks], BF[ni][ks], acc[QM][QN][mi][ni], 0, 0, 0);        \
    __builtin_amdgcn_s_setprio(0);

template<int EPI>
__global__ __launch_bounds__(512, 2) void gemm_8ph(
    const __hip_bfloat16* __restrict__ A, const __hip_bfloat16* __restrict__ B,
    void* __restrict__ Cv, int K, int lda, int ldb, int ldc, int gx) {
    __shared__ __hip_bfloat16 ldsA[2][2][8192];   // [buf][half][128*64]
    __shared__ __hip_bfloat16 ldsB[2][2][8192];
    const int tid = threadIdx.x;
    const int nwg = gridDim.x;
    const int orig = blockIdx.x;
    const int wgid = (orig & 7) * (nwg >> 3) + (orig >> 3);   // nwg % 8 == 0
    const int bx = wgid % gx, by = wgid / gx;

    const __hip_bfloat16* Ab = A + (long)bx * 256 * lda;
    const __hip_bfloat16* Bb = B + (long)by * 256 * ldb;

    const int w = tid >> 6, l = tid & 63;
    const int wm = w >> 2, wn = w & 3;   // 2 x 4 wave grid
    const int fr = l & 15, g = l >> 4;
    const int sRow0 = tid >> 3;          // staging row (+64*i)
    const int sCh = tid & 7;             // staging 16B chunk in 128B row

    floatx4 acc[2][2][4][2] = {};
    bf16x8 af[4][2], bf0[2][2], bf1[2][2];

    auto stage = [&](const __hip_bfloat16* src, int ld, int k0, __hip_bfloat16* dst) {
        #pragma unroll
        for (int i = 0; i < 2; ++i) {
            int row = sRow0 + i * 64;
            int cs = (sCh ^ (row & 7)) * 8;
            // LDS dest: row*128B + sCh*16B = tid*16B (i-group 1 at +8192B = 64 rows)
            __builtin_amdgcn_global_load_lds(
                (kGlb*)(src + (long)row * ld + k0 + cs),
                (kLds*)((char*)dst + i * 8192 + tid * 16), 16, 0, 0);
        }
    };

    const int nt = K >> 6;   // K multiple of 64, nt >= 2 at all call sites
    // prologue: A0(0), B0(0), B1(0), A1(0), A0(1), B0(1)  (order matters for vmcnt math)
    stage(Ab,             lda, 0,  &ldsA[0][0][0]);
    stage(Bb,             ldb, 0,  &ldsB[0][0][0]);
    stage(Bb + 128 * ldb, ldb, 0,  &ldsB[0][1][0]);
    stage(Ab + 128 * lda, lda, 0,  &ldsA[0][1][0]);
    stage(Ab,             lda, 64, &ldsA[1][0][0]);
    stage(Bb,             ldb, 64, &ldsB[1][0][0]);

    for (int t = 0; t < nt - 1; ++t) {
        const int b = t & 1, nb = b ^ 1;
        // ---- ph0: quadrant (0,0); stage B1(t+1) ----
        asm volatile("s_waitcnt vmcnt(8)" ::: "memory");
        __builtin_amdgcn_s_barrier();
        stage(Bb + 128 * ldb, ldb, (t + 1) * 64, &ldsB[nb][1][0]);
        RD_AF(b, 0);
        RD_BF(bf0, b, 0);
        asm volatile("s_waitcnt lgkmcnt(0)" ::: "memory");
        __builtin_amdgcn_sched_barrier(0);
        MM(0, 0, bf0);
        __builtin_amdgcn_sched_barrier(0);
        // ---- ph1: quadrant (0,1); stage A1(t+1) ----
        asm volatile("s_waitcnt vmcnt(8)" ::: "memory");
        __builtin_amdgcn_s_barrier();
        stage(Ab + 128 * lda, lda, (t + 1) * 64, &ldsA[nb][1][0]);
        RD_BF(bf1, b, 1);
        asm volatile("s_waitcnt lgkmcnt(0)" ::: "memory");
        __builtin_amdgcn_sched_barrier(0);
        MM(0, 1, bf1);
        __builtin_amdgcn_sched_barrier(0);
        // ---- ph2: quadrant (1,0); stage A0(t+2) ----
        asm volatile("s_waitcnt vmcnt(8)" ::: "memory");
        __builtin_amdgcn_s_barrier();
        if (t + 2 < nt) stage(Ab, lda, (t + 2) * 64, &ldsA[b][0][0]);
        RD_AF(b, 1);
        asm volatile("s_waitcnt lgkmcnt(0)" ::: "memory");
        __builtin_amdgcn_sched_barrier(0);
        MM(1, 0, bf0);
        __builtin_amdgcn_sched_barrier(0);
        // ---- ph3: quadrant (1,1); stage B0(t+2); no waits ----
        __builtin_amdgcn_s_barrier();
        if (t + 2 < nt) stage(Bb, ldb, (t + 2) * 64, &ldsB[b][0][0]);
        MM(1, 1, bf1);
        __builtin_amdgcn_sched_barrier(0);
    }
    // ---- peeled last tile: waits 4 / 2 / 0 / none, no stages ----
    {
        const int b = (nt - 1) & 1;
        asm volatile("s_waitcnt vmcnt(4)" ::: "memory");
        __builtin_amdgcn_s_barrier();
        RD_AF(b, 0);
        RD_BF(bf0, b, 0);
        asm volatile("s_waitcnt lgkmcnt(0)" ::: "memory");
        __builtin_amdgcn_sched_barrier(0);
        MM(0, 0, bf0);
        asm volatile("s_waitcnt vmcnt(2)" ::: "memory");
        __builtin_amdgcn_s_barrier();
        RD_BF(bf1, b, 1);
        asm volatile("s_waitcnt lgkmcnt(0)" ::: "memory");
        __builtin_amdgcn_sched_barrier(0);
        MM(0, 1, bf1);
        asm volatile("s_waitcnt vmcnt(0)" ::: "memory");
        __builtin_amdgcn_s_barrier();
        RD_AF(b, 1);
        asm volatile("s_waitcnt lgkmcnt(0)" ::: "memory");
        __builtin_amdgcn_sched_barrier(0);
        MM(1, 0, bf0);
        MM(1, 1, bf1);
    }

    const long cBase = (long)bx * 256 * ldc + (long)by * 256;
    const int rg = (l >> 4) * 4;
    #pragma unroll
    for (int qm = 0; qm < 2; ++qm)
    #pragma unroll
    for (int qn = 0; qn < 2; ++qn)
    #pragma unroll
    for (int mi = 0; mi < 4; ++mi)
    #pragma unroll
    for (int ni = 0; ni < 2; ++ni)
    #pragma unroll
    for (int r = 0; r < 4; ++r) {
        int row = qm * 128 + wm * 64 + mi * 16 + rg + r;
        int col = qn * 128 + wn * 32 + ni * 16 + fr;
        long idx = cBase + (long)row * ldc + col;
        float v = acc[qm][qn][mi][ni][r];
        if constexpr (EPI == 3) {
            ((float*)Cv)[idx] = tanhf(v * (1.f / 30.f)) * 30.f;
        } else {
            int colg = by * 256 + col;
            float o = v;
            if (colg < 8192)
                o = 0.5f * v * (1.f + tanhf(0.7978845608f * (v + 0.044715f * v * v * v)));
            ((__hip_bfloat16*)Cv)[idx] = __float2bfloat16(o);
        }
    }
}

// ---------------- generic pipelined GEMM (128x128 path, unchanged) ----------------
template<int EPI, int WM, int WN, int MI, int NI>
__global__ __launch_bounds__(WM*WN*64, 2) void gemm_pipe(
    const __hip_bfloat16* __restrict__ A, const __hip_bfloat16* __restrict__ B,
    void* __restrict__ Cv, int K, int lda, int ldb, int ldc,
    long aBatch, long bBatch, long cBatch, int bzDiv, int gx, int kMode) {
    constexpr int T  = WM * WN * 64;
    constexpr int BM = WM * MI * 16;
    constexpr int BN = WN * NI * 16;
    constexpr int AE = BM * 32;
    constexpr int BE = BN * 32;
    __shared__ __hip_bfloat16 lds[4][AE + BE];

    const int tid = threadIdx.x;
    const int nwg = gridDim.x;
    const int orig = blockIdx.x;
    const int wgid = (orig & 7) * (nwg >> 3) + (orig >> 3);
    const int bx = wgid % gx, by = wgid / gx;
    const int bz = blockIdx.z;

    int kstart = 0, kend = K;
    if (kMode == 1) { if (by > bx) return; }
    else if (kMode == 2) { if (by > bx || bx - by >= 9) return; }
    else if (kMode == 3) { kend = min(K, (bx + 1) * BM); }
    else if (kMode == 4) { kend = min(K, (bx + 1) * BM); kstart = max(0, (bx - 1024 / BM) * BM); }

    const __hip_bfloat16* Ab = A + (long)bz * aBatch + (long)bx * BM * lda;
    const __hip_bfloat16* Bb = B + (long)(bz / bzDiv) * bBatch + (long)by * BN * ldb;

    const int w = tid >> 6, l = tid & 63;
    const int wm = w / WN, wn = w % WN;
    const int wrow = wm * MI * 16, wcol = wn * NI * 16;
    const int fr = l & 15, g = l >> 4;
    const int sR = tid >> 2;
    const int sc = tid & 3;

    floatx4 acc[MI][NI] = {};
    bf16x8 bfv[NI];
    bf16x8 af[MI / 2];

    auto stageA = [&](int t, int buf) {
        const int k0 = kstart + t * 32;
        #pragma unroll
        for (int i = 0; i < 2; ++i) {
            int row = sR + i * (T / 4);
            int scol = ((sc ^ ((row >> 1) & 3)) << 3);
            __builtin_amdgcn_global_load_lds(
                (kGlb*)(Ab + (long)row * lda + k0 + scol),
                (kLds*)(&lds[buf][0] + tid * 8 + i * (T * 8)), 16, 0, 0);
        }
    };
    auto stageB = [&](int t, int buf) {
        const int k0 = kstart + t * 32;
        #pragma unroll
        for (int i = 0; i < 2; ++i) {
            int row = sR + i * (T / 4);
            int scol = ((sc ^ ((row >> 1) & 3)) << 3);
            __builtin_amdgcn_global_load_lds(
                (kGlb*)(Bb + (long)row * ldb + k0 + scol),
                (kLds*)(&lds[buf][AE] + tid * 8 + i * (T * 8)), 16, 0, 0);
        }
    };

    auto phase0 = [&](int buf, int t3, bool doStage) {
        const char* AsB = (const char*)&lds[buf][0];
        const char* BsB = (const char*)&lds[buf][AE];
        #pragma unroll
        for (int mi = 0; mi < MI / 2; ++mi) {
            int ra = wrow + mi * 16 + fr;
            af[mi] = *(const bf16x8*)(AsB + ra * 64 + ((g ^ ((ra >> 1) & 3)) << 4));
        }
        #pragma unroll
        for (int ni = 0; ni < NI; ++ni) {
            int rb = wcol + ni * 16 + fr;
            bfv[ni] = *(const bf16x8*)(BsB + rb * 64 + ((g ^ ((rb >> 1) & 3)) << 4));
        }
        if (doStage) stageA(t3, t3 & 3);
        __builtin_amdgcn_s_barrier();
        asm volatile("s_waitcnt lgkmcnt(0)" ::: "memory");
        __builtin_amdgcn_sched_barrier(0);
        __builtin_amdgcn_s_setprio(1);
        #pragma unroll
        for (int mi = 0; mi < MI / 2; ++mi)
            #pragma unroll
            for (int ni = 0; ni < NI; ++ni)
                acc[mi][ni] = __builtin_amdgcn_mfma_f32_16x16x32_bf16(af[mi], bfv[ni], acc[mi][ni], 0, 0, 0);
        __builtin_amdgcn_s_setprio(0);
        __builtin_amdgcn_sched_barrier(0);
        __builtin_amdgcn_s_barrier();
    };

    auto phase1 = [&](int buf, int t3, bool doStage, int vm) {
        const char* AsB = (const char*)&lds[buf][0];
        #pragma unroll
        for (int mi = 0; mi < MI / 2; ++mi) {
            int ra = wrow + (MI / 2 + mi) * 16 + fr;
            af[mi] = *(const bf16x8*)(AsB + ra * 64 + ((g ^ ((ra >> 1) & 3)) << 4));
        }
        if (doStage) stageB(t3, t3 & 3);
        if (vm == 8)      asm volatile("s_waitcnt vmcnt(8)" ::: "memory");
        else if (vm == 4) asm volatile("s_waitcnt vmcnt(4)" ::: "memory");
        else if (vm == 0) asm volatile("s_waitcnt vmcnt(0)" ::: "memory");
        __builtin_amdgcn_s_barrier();
        asm volatile("s_waitcnt lgkmcnt(0)" ::: "memory");
        __builtin_amdgcn_sched_barrier(0);
        __builtin_amdgcn_s_setprio(1);
        #pragma unroll
        for (int mi = 0; mi < MI / 2; ++mi)
            #pragma unroll
            for (int ni = 0; ni < NI; ++ni)
                acc[MI / 2 + mi][ni] = __builtin_amdgcn_mfma_f32_16x16x32_bf16(af[mi], bfv[ni], acc[MI / 2 + mi][ni], 0, 0, 0);
        __builtin_amdgcn_s_setprio(0);
        __builtin_amdgcn_sched_barrier(0);
        __builtin_amdgcn_s_barrier();
    };

    const int nt = (kend - kstart) >> 5;
    stageA(0, 0); stageB(0, 0);
    stageA(1, 1); stageB(1, 1);
    stageA(2, 2); stageB(2, 2);
    asm volatile("s_waitcnt vmcnt(8)" ::: "memory");
    __builtin_amdgcn_s_barrier();

    for (int t = 0; t < nt - 3; ++t) {
        const int b = t & 3;
        phase0(b, t + 3, true);
        phase1(b, t + 3, true, 8);
    }
    phase0((nt - 3) & 3, 0, false); phase1((nt - 3) & 3, 0, false, 4);
    phase0((nt - 2) & 3, 0, false); phase1((nt - 2) & 3, 0, false, 0);
    phase0((nt - 1) & 3, 0, false); phase1((nt - 1) & 3, 0, false, -1);

    const long cBase = (long)bz * cBatch + (long)bx * BM * ldc + (long)by * BN;
    const int rg = (l >> 4) * 4;
    #pragma unroll
    for (int mi = 0; mi < MI; ++mi) {
        #pragma unroll
        for (int ni = 0; ni < NI; ++ni) {
            #pragma unroll
            for (int r = 0; r < 4; ++r) {
                int row = wrow + mi * 16 + rg + r;
                int col = wcol + ni * 16 + fr;
                long idx = cBase + (long)row * ldc + col;
                float v = acc[mi][ni][r];
                if constexpr (EPI == 0) {
                    ((float*)Cv)[idx] = v;
                } else {
                    ((__hip_bfloat16*)Cv)[idx] = __float2bfloat16(v);
                }
            }
        }
    }
}

// ---------------- fallback GEMMs (used only if ws too small) ----------------
template<int EPI>
__global__ __launch_bounds__(256) void gemm_bf16(
    const __hip_bfloat16* __restrict__ A, const __hip_bfloat16* __restrict__ B,
    void* __restrict__ Cv, int K, int lda, int ldb, int ldc,
    long aBatch, long bBatch, long cBatch, int bzDiv, int gx, int kMode) {
    __shared__ __hip_bfloat16 As[128 * 32];
    __shared__ __hip_bfloat16 Bs[128 * 32];
    const int tid = threadIdx.x;
    const int nwg = gridDim.x;
    const int orig = blockIdx.x;
    const int wgid = (orig & 7) * (nwg >> 3) + (orig >> 3);
    const int bx = wgid % gx, by = wgid / gx;
    const int bz = blockIdx.z;

    int kstart = 0, kend = K;
    if (kMode == 1) { if (by > bx) return; }
    else if (kMode == 2) { if (by > bx || bx - by >= 9) return; }
    else if (kMode == 3) { kend = min(K, (bx + 1) * 128); }
    else if (kMode == 4) { kend = min(K, (bx + 1) * 128); kstart = max(0, (bx - 8) * 128); }

    const __hip_bfloat16* Ab = A + (long)bz * aBatch + (long)bx * 128 * lda;
    const __hip_bfloat16* Bb = B + (long)(bz / bzDiv) * bBatch + (long)by * 128 * ldb;

    const int w = tid >> 6, l = tid & 63;
    int srow[2], scsrc[2], sdst[2];
    #pragma unroll
    for (int i = 0; i < 2; ++i) {
        int o = w * 2048 + i * 1024 + l * 16;
        int row = o >> 6;
        int chunk = (o >> 4) & 3;
        srow[i]  = row;
        scsrc[i] = (chunk ^ ((row >> 1) & 3)) * 8;
        sdst[i]  = w * 1024 + i * 512;
    }
    const int wr = (w >> 1) * 64, wc = (w & 1) * 64;
    const int fr = l & 15;
    const int g  = l >> 4;
    floatx4 acc[4][4] = {};
    for (int k0 = kstart; k0 < kend; k0 += 32) {
        __syncthreads();
        #pragma unroll
        for (int i = 0; i < 2; ++i) {
            __builtin_amdgcn_global_load_lds(
                (kGlb*)(Ab + (long)srow[i] * lda + k0 + scsrc[i]),
                (kLds*)(As + sdst[i]), 16, 0, 0);
            __builtin_amdgcn_global_load_lds(
                (kGlb*)(Bb + (long)srow[i] * ldb + k0 + scsrc[i]),
                (kLds*)(Bs + sdst[i]), 16, 0, 0);
        }
        __syncthreads();
        bf16x8 af[4], bfr[4];
        const char* AsB = (const char*)As;
        const char* BsB = (const char*)Bs;
        #pragma unroll
        for (int i = 0; i < 4; ++i) {
            int ra = wr + i * 16 + fr;
            af[i] = *(const bf16x8*)(AsB + ra * 64 + (((g ^ ((ra >> 1) & 3))) << 4));
        }
        #pragma unroll
        for (int j = 0; j < 4; ++j) {
            int rb = wc + j * 16 + fr;
            bfr[j] = *(const bf16x8*)(BsB + rb * 64 + (((g ^ ((rb >> 1) & 3))) << 4));
        }
        #pragma unroll
        for (int i = 0; i < 4; ++i)
            #pragma unroll
            for (int j = 0; j < 4; ++j)
                acc[i][j] = __builtin_amdgcn_mfma_f32_16x16x32_bf16(af[i], bfr[j], acc[i][j], 0, 0, 0);
    }
    const long cTile = (long)bz * cBatch + (long)bx * 128 * ldc + (long)by * 128;
    const int rg = (l >> 4) * 4;
    #pragma unroll
    for (int i = 0; i < 4; ++i)
        #pragma unroll
        for (int j = 0; j < 4; ++j)
            #pragma unroll
            for (int r = 0; r < 4; ++r) {
                int row = wr + i * 16 + rg + r;
                int col = wc + j * 16 + fr;
                long idx = cTile + (long)row * ldc + col;
                float v = acc[i][j][r];
                if constexpr (EPI == 0) ((float*)Cv)[idx] = v;
                else ((__hip_bfloat16*)Cv)[idx] = __float2bfloat16(v);
            }
}

template<int EPI>
__global__ __launch_bounds__(256) void gemm_f32w(
    const __hip_bfloat16* __restrict__ A, const float* __restrict__ Bv,
    void* __restrict__ Cv, int K, int lda, int ldb, int ldc) {
    __shared__ __hip_bfloat16 As[128][32];
    __shared__ __hip_bfloat16 Bs[128][32];
    const int tid = threadIdx.x;
    const __hip_bfloat16* Ab = A + (long)blockIdx.x * 128 * lda;
    const float* Bb = Bv + (long)blockIdx.y * 128 * ldb;
    const int wid = tid >> 6, lane = tid & 63;
    const int wr = (wid >> 1) * 64, wc = (wid & 1) * 64;
    const int fr = lane & 15;
    const int kb = (lane >> 4) * 8;
    floatx4 acc[4][4] = {};
    for (int k0 = 0; k0 < K; k0 += 32) {
        __syncthreads();
        #pragma unroll
        for (int it = 0; it < 2; ++it) {
            int slot = tid + it * 256;
            int r = slot >> 2, c8 = (slot & 3) * 8;
            *reinterpret_cast<uint4*>(&As[r][c8]) =
                *reinterpret_cast<const uint4*>(Ab + (long)r * lda + k0 + c8);
        }
        #pragma unroll
        for (int it = 0; it < 4; ++it) {
            int slot = tid + it * 256;
            int r = slot >> 3, c4 = (slot & 7) * 4;
            float4 f = *reinterpret_cast<const float4*>(Bb + (long)r * ldb + k0 + c4);
            __hip_bfloat16 t4[4] = {__float2bfloat16(f.x), __float2bfloat16(f.y),
                                    __float2bfloat16(f.z), __float2bfloat16(f.w)};
            *reinterpret_cast<ushort4*>(&Bs[r][c4]) = *reinterpret_cast<const ushort4*>(t4);
        }
        __syncthreads();
        bf16x8 af[4], bfr[4];
        #pragma unroll
        for (int i = 0; i < 4; ++i)
            af[i] = *reinterpret_cast<const bf16x8*>(&As[wr + i * 16 + fr][kb]);
        #pragma unroll
        for (int j = 0; j < 4; ++j)
            bfr[j] = *reinterpret_cast<const bf16x8*>(&Bs[wc + j * 16 + fr][kb]);
        #pragma unroll
        for (int i = 0; i < 4; ++i)
            #pragma unroll
            for (int j = 0; j < 4; ++j)
                acc[i][j] = __builtin_amdgcn_mfma_f32_16x16x32_bf16(af[i], bfr[j], acc[i][j], 0, 0, 0);
    }
    const long cTile = (long)blockIdx.x * 128 * ldc + (long)blockIdx.y * 128;
    const int rg = (lane >> 4) * 4;
    #pragma unroll
    for (int i = 0; i < 4; ++i)
        #pragma unroll
        for (int j = 0; j < 4; ++j)
            #pragma unroll
            for (int r = 0; r < 4; ++r) {
                int row = wr + i * 16 + rg + r;
                int col = wc + j * 16 + fr;
                long idx = cTile + (long)row * ldc + col;
                float v = acc[i][j][r];
                if constexpr (EPI == 0) ((float*)Cv)[idx] = v;
                else if constexpr (EPI == 1) ((__hip_bfloat16*)Cv)[idx] = __float2bfloat16(v);
                else if constexpr (EPI == 2) {
                    float gg = 0.5f * v * (1.f + tanhf(0.7978845608f * (v + 0.044715f * v * v * v)));
                    ((__hip_bfloat16*)Cv)[idx] = __float2bfloat16(gg);
                } else ((float*)Cv)[idx] = tanhf(v * (1.f / 30.f)) * 30.f;
            }
}

// ---------------- host ----------------
extern "C" void kernel_launch(void* const* d_in, const int* in_sizes, int n_in,
                              void* d_out, int out_size, void* d_ws, size_t ws_size,
                              hipStream_t stream) {
    const int*   ids    = (const int*)d_in[0];
    const float* embedW = (const float*)d_in[1];
    const float* wq     = (const float*)d_in[2];
    const float* wk     = (const float*)d_in[3];
    const float* wv     = (const float*)d_in[4];
    const float* wo     = (const float*)d_in[5];
    const float* wg     = (const float*)d_in[6];
    const float* wu     = (const float*)d_in[7];
    const float* wd     = (const float*)d_in[8];
    const float* ln_in  = (const float*)d_in[9];
    const float* ln_pa  = (const float*)d_in[10];
    const float* ln_pf  = (const float*)d_in[11];
    const float* ln_pff = (const float*)d_in[12];
    const float* ln_f   = (const float*)d_in[13];
    const float* w_lm   = (const float*)d_in[14];
    float* out = (float*)d_out;

    char* ws = (char*)d_ws;
    size_t off = 0;
    auto alloc = [&](size_t bytes) -> void* {
        size_t o = (off + 255) & ~(size_t)255;
        off = o + bytes;
        return (void*)(ws + o);
    };

    float* h            = (float*)alloc((size_t)S * D * 4);
    __hip_bfloat16* xb  = (__hip_bfloat16*)alloc((size_t)S * D * 2);
    __hip_bfloat16* qkvb = (__hip_bfloat16*)alloc((size_t)S * 4096 * 2); // q|k|v packed
    __hip_bfloat16* vT  = (__hip_bfloat16*)alloc((size_t)NKV * HD * S * 2);
    __hip_bfloat16* ab  = (__hip_bfloat16*)alloc((size_t)S * NH * HD * 2);
    float* tmpf         = (float*)alloc((size_t)S * D * 4);
    __hip_bfloat16* gu  = (__hip_bfloat16*)alloc((size_t)S * 16384 * 2); // gate|up packed
    float* cosb         = (float*)alloc((size_t)S * 128 * 4);
    float* sinb         = (float*)alloc((size_t)S * 128 * 4);
    float* scores       = (float*)alloc((size_t)NH * S * S * 4);
    __hip_bfloat16* probs = (__hip_bfloat16*)alloc((size_t)NH * S * S * 2);

    const long SLq = 2048L * 2048, SLkv = 1024L * 2048, SLff = 8192L * 2048;
    const long nWlm = (long)VOCAB * D;
    __hip_bfloat16* wqkvb = (__hip_bfloat16*)alloc(4L * 4096 * 2048 * 2);
    __hip_bfloat16* wgub  = (__hip_bfloat16*)alloc(4L * 16384 * 2048 * 2);
    __hip_bfloat16* wob   = (__hip_bfloat16*)alloc(4L * SLq * 2);
    __hip_bfloat16* wdb   = (__hip_bfloat16*)alloc(4L * SLff * 2);
    __hip_bfloat16* wlmb  = (__hip_bfloat16*)alloc(nWlm * 2);
    const bool big = (off <= ws_size);
    (void)in_sizes; (void)n_in; (void)out_size;

    rope_table_kernel<<<dim3(S), dim3(128), 0, stream>>>(cosb, sinb);
    embed_kernel<<<dim3(D / 256, S), dim3(256), 0, stream>>>(ids, embedW, h);

    auto cvt = [&](const float* s, __hip_bfloat16* dp, long n) {
        long n8 = n / 8;
        long want = (n8 + 255) / 256;
        int blocks = (int)(want < 2048 ? want : 2048);
        cvt_bf16_kernel<<<dim3(blocks), dim3(256), 0, stream>>>(s, dp, n8);
    };
    if (big) {
        for (int l = 0; l < NLAYER; ++l) {
            cvt(wq + l * SLq,  wqkvb + (size_t)l * 4096 * 2048,                SLq);
            cvt(wk + l * SLkv, wqkvb + (size_t)l * 4096 * 2048 + 2048L * 2048, SLkv);
            cvt(wv + l * SLkv, wqkvb + (size_t)l * 4096 * 2048 + 3072L * 2048, SLkv);
            cvt(wg + l * SLff, wgub + (size_t)l * 16384 * 2048,                SLff);
            cvt(wu + l * SLff, wgub + (size_t)l * 16384 * 2048 + 8192L * 2048, SLff);
        }
        cvt(wo, wob, 4L * SLq);
        cvt(wd, wdb, 4L * SLff);
        cvt(w_lm, wlmb, nWlm);
    }

    // launchers
    auto p8 = [&](int epi, const __hip_bfloat16* A, const __hip_bfloat16* B, void* C,
                  int K, int lda, int ldb, int ldc, int gx, int gy) {
        dim3 grid(gx * gy, 1, 1);
        if (epi == 3) gemm_8ph<3><<<grid, 512, 0, stream>>>(A, B, C, K, lda, ldb, ldc, gx);
        else          gemm_8ph<4><<<grid, 512, 0, stream>>>(A, B, C, K, lda, ldb, ldc, gx);
    };
    auto p128 = [&](int epi, const __hip_bfloat16* A, const __hip_bfloat16* B, void* C,
                    int K, int lda, int ldb, int ldc, int gx, int gy, int gz,
                    long aB, long bB, long cB, int bzDiv, int kMode) {
        dim3 grid(gx * gy, 1, gz);
        switch (epi) {
        case 0: gemm_pipe<0, 2, 2, 4, 4><<<grid, 256, 0, stream>>>(A, B, C, K, lda, ldb, ldc, aB, bB, cB, bzDiv, gx, kMode); break;
        default: gemm_pipe<1, 2, 2, 4, 4><<<grid, 256, 0, stream>>>(A, B, C, K, lda, ldb, ldc, aB, bB, cB, bzDiv, gx, kMode); break;
        }
    };

    for (int l = 0; l < NLAYER; ++l) {
        int isLocal = (l % 2 == 0) ? 1 : 0;
        rms_bf16_kernel<<<dim3(S), dim3(256), 0, stream>>>(h, ln_in + l * D, xb);
        if (big) {
            p128(1, xb, wqkvb + (size_t)l * 4096 * 2048, qkvb, D, D, D, 4096, 16, 32, 1, 0, 0, 0, 1, 0);
        } else {
            gemm_f32w<1><<<dim3(16, 16), 256, 0, stream>>>(xb, wq + l * SLq, qkvb, D, D, D, 4096);
            gemm_f32w<1><<<dim3(16, 8), 256, 0, stream>>>(xb, wk + l * SLkv, qkvb + 2048, D, D, D, 4096);
            gemm_f32w<1><<<dim3(16, 8), 256, 0, stream>>>(xb, wv + l * SLkv, qkvb + 3072, D, D, D, 4096);
        }
        rope_kernel<<<dim3(S, NH), dim3(128), 0, stream>>>(qkvb, cosb, sinb, 4096);
        rope_kernel<<<dim3(S, NKV), dim3(128), 0, stream>>>(qkvb + 2048, cosb, sinb, 4096);
        transpose_v_kernel<<<dim3(S / 64, HD / 64, NKV), 256, 0, stream>>>(qkvb + 3072, vT, 4096);
        if (big) {
            p128(0, qkvb, qkvb + 2048, scores, HD, 4096, 4096, S, 16, 16, NH,
                 (long)HD, (long)HD, (long)S * S, 2, isLocal ? 2 : 1);
        } else {
            gemm_bf16<0><<<dim3(256, 1, NH), 256, 0, stream>>>(
                qkvb, qkvb + 2048, scores, HD, 4096, 4096, S,
                (long)HD, (long)HD, (long)S * S, 2, 16, isLocal ? 2 : 1);
        }
        softmax_kernel<<<dim3(S, NH), dim3(256), 0, stream>>>(scores, probs, isLocal);
        if (big) {
            p128(1, probs, vT, ab, S, S, S, NH * HD, 16, 2, NH,
                 (long)S * S, (long)HD * S, (long)HD, 2, isLocal ? 4 : 3);
        } else {
            gemm_bf16<1><<<dim3(32, 1, NH), 256, 0, stream>>>(
                probs, vT, ab, S, S, S, NH * HD,
                (long)S * S, (long)HD * S, (long)HD, 2, 16, isLocal ? 4 : 3);
        }
        if (big) {
            p128(0, ab, wob + (size_t)l * SLq, tmpf, NH * HD, NH * HD, NH * HD, D, 16, 16, 1, 0, 0, 0, 1, 0);
        } else {
            gemm_f32w<0><<<dim3(16, 16), 256, 0, stream>>>(ab, wo + l * SLq, tmpf, NH * HD, NH * HD, NH * HD, D);
        }
        resid_rms_kernel<<<dim3(S), dim3(256), 0, stream>>>(h, tmpf, ln_pa + l * D);
        rms_bf16_kernel<<<dim3(S), dim3(256), 0, stream>>>(h, ln_pf + l * D, xb);
        if (big) {
            p8(4, xb, wgub + (size_t)l * 16384 * 2048, gu, D, D, D, 16384, 8, 64);
        } else {
            gemm_f32w<2><<<dim3(16, 64), 256, 0, stream>>>(xb, wg + l * SLff, gu, D, D, D, 16384);
            gemm_f32w<1><<<dim3(16, 64), 256, 0, stream>>>(xb, wu + l * SLff, gu + 8192, D, D, D, 16384);
        }
        mul_gu_kernel<<<dim3((S * FF) / (256 * 8)), 256, 0, stream>>>(gu);
        if (big) {
            p128(0, gu, wdb + (size_t)l * SLff, tmpf, FF, 16384, FF, D, 16, 16, 1, 0, 0, 0, 1, 0);
        } else {
            gemm_f32w<0><<<dim3(16, 16), 256, 0, stream>>>(gu, wd + l * SLff, tmpf, FF, 16384, FF, D);
        }
        resid_rms_kernel<<<dim3(S), dim3(256), 0, stream>>>(h, tmpf, ln_pff + l * D);
    }

    rms_bf16_kernel<<<dim3(S), dim3(256), 0, stream>>>(h, ln_f, xb);
    if (big) {
        p8(3, xb, wlmb, out, D, D, D, VOCAB, 8, VOCAB / 256);
    } else {
        gemm_f32w<3><<<dim3(16, VOCAB / 128), 256, 0, stream>>>(xb, w_lm, out, D, D, D, VOCAB);
    }
}

// Round 7
// 2593.519 us; speedup vs baseline: 1.0658x; 1.0658x over previous
//
#include <hip/hip_runtime.h>
#include <hip/hip_bf16.h>

typedef __attribute__((ext_vector_type(8))) __bf16 bf16x8;
typedef __attribute__((ext_vector_type(4))) float floatx4;

typedef __attribute__((address_space(1))) const unsigned char kGlb;
typedef __attribute__((address_space(3))) unsigned char kLds;

static constexpr int S = 2048;
static constexpr int D = 2048;
static constexpr int HD = 256;
static constexpr int NH = 8;
static constexpr int NKV = 4;
static constexpr int NLAYER = 4;
static constexpr int VOCAB = 32000;
static constexpr int FF = 8192;
static constexpr int WINDOW = 1024;

// ---------------- block reduction helpers (256 threads = 4 waves) ----------------
__device__ __forceinline__ float blk_sum(float v) {
    __shared__ float sm[4];
    #pragma unroll
    for (int o = 32; o > 0; o >>= 1) v += __shfl_down(v, o, 64);
    int lane = threadIdx.x & 63, w = threadIdx.x >> 6;
    __syncthreads();
    if (lane == 0) sm[w] = v;
    __syncthreads();
    return sm[0] + sm[1] + sm[2] + sm[3];
}

__device__ __forceinline__ float blk_max(float v) {
    __shared__ float sm[4];
    #pragma unroll
    for (int o = 32; o > 0; o >>= 1) v = fmaxf(v, __shfl_down(v, o, 64));
    int lane = threadIdx.x & 63, w = threadIdx.x >> 6;
    __syncthreads();
    if (lane == 0) sm[w] = v;
    __syncthreads();
    return fmaxf(fmaxf(sm[0], sm[1]), fmaxf(sm[2], sm[3]));
}

// ---------------- elementwise kernels ----------------
__global__ void embed_kernel(const int* __restrict__ ids, const float* __restrict__ E,
                             float* __restrict__ h) {
    int d = blockIdx.x * 256 + threadIdx.x;
    int s = blockIdx.y;
    h[(long)s * D + d] = E[(long)ids[s] * D + d] * 45.25483399593904f; // sqrt(2048)
}

__global__ void rope_table_kernel(float* __restrict__ c, float* __restrict__ sn) {
    int i = threadIdx.x;   // 0..127
    int p = blockIdx.x;    // 0..S-1
    float inv = powf(10000.f, -(float)i / 128.f);
    float a = (float)p * inv;
    c[p * 128 + i] = cosf(a);
    sn[p * 128 + i] = sinf(a);
}

// fp32 -> bf16 conversion (grid-stride, 8 elems/thread/iter)
__global__ void cvt_bf16_kernel(const float* __restrict__ src, __hip_bfloat16* __restrict__ dst,
                                long n8) {
    long stride = (long)gridDim.x * 256;
    for (long i = (long)blockIdx.x * 256 + threadIdx.x; i < n8; i += stride) {
        long o = i * 8;
        float4 a = *(const float4*)(src + o);
        float4 b = *(const float4*)(src + o + 4);
        __hip_bfloat16 h8[8] = {
            __float2bfloat16(a.x), __float2bfloat16(a.y),
            __float2bfloat16(a.z), __float2bfloat16(a.w),
            __float2bfloat16(b.x), __float2bfloat16(b.y),
            __float2bfloat16(b.z), __float2bfloat16(b.w)};
        *(uint4*)(dst + o) = *(const uint4*)h8;
    }
}

// fp32 (rows x 2048) -> bf16 at interleaved rows: dst row = 2*row + half
__global__ void cvt_inter_kernel(const float* __restrict__ src, __hip_bfloat16* __restrict__ dst,
                                 int half, long n8) {
    long stride = (long)gridDim.x * 256;
    for (long i = (long)blockIdx.x * 256 + threadIdx.x; i < n8; i += stride) {
        long o = i * 8;
        long row = o >> 11, col = o & 2047;
        float4 a = *(const float4*)(src + o);
        float4 b = *(const float4*)(src + o + 4);
        __hip_bfloat16 h8[8] = {
            __float2bfloat16(a.x), __float2bfloat16(a.y),
            __float2bfloat16(a.z), __float2bfloat16(a.w),
            __float2bfloat16(b.x), __float2bfloat16(b.y),
            __float2bfloat16(b.z), __float2bfloat16(b.w)};
        *(uint4*)(dst + ((row * 2 + half) << 11) + col) = *(const uint4*)h8;
    }
}

// x = rms(h, w) -> bf16
__global__ void rms_bf16_kernel(const float* __restrict__ h, const float* __restrict__ w,
                                __hip_bfloat16* __restrict__ o) {
    int s = blockIdx.x;
    const float* row = h + (long)s * D;
    float vals[8], ss = 0.f;
    #pragma unroll
    for (int t = 0; t < 8; ++t) {
        int j = t * 256 + threadIdx.x;
        float v = row[j]; vals[t] = v; ss += v * v;
    }
    ss = blk_sum(ss);
    float r = rsqrtf(ss * (1.f / D) + 1e-6f);
    #pragma unroll
    for (int t = 0; t < 8; ++t) {
        int j = t * 256 + threadIdx.x;
        o[(long)s * D + j] = __float2bfloat16(vals[t] * r * (1.f + w[j]));
    }
}

// h += rms(t, w)
__global__ void resid_rms_kernel(float* __restrict__ h, const float* __restrict__ tt,
                                 const float* __restrict__ w) {
    int s = blockIdx.x;
    const float* row = tt + (long)s * D;
    float* hr = h + (long)s * D;
    float vals[8], ss = 0.f;
    #pragma unroll
    for (int t = 0; t < 8; ++t) {
        int j = t * 256 + threadIdx.x;
        float v = row[j]; vals[t] = v; ss += v * v;
    }
    ss = blk_sum(ss);
    float r = rsqrtf(ss * (1.f / D) + 1e-6f);
    #pragma unroll
    for (int t = 0; t < 8; ++t) {
        int j = t * 256 + threadIdx.x;
        hr[j] += vals[t] * r * (1.f + w[j]);
    }
}

// in-place RoPE on rows with stride ldx; head offset hh*HD; 128 threads per (s, head)
__global__ void rope_kernel(__hip_bfloat16* __restrict__ x, const float* __restrict__ cb,
                            const float* __restrict__ sb, int ldx) {
    int s = blockIdx.x, hh = blockIdx.y, i = threadIdx.x; // i in 0..127
    __hip_bfloat16* p = x + (long)s * ldx + hh * HD;
    float x1 = __bfloat162float(p[i]);
    float x2 = __bfloat162float(p[128 + i]);
    float c = cb[s * 128 + i], sn = sb[s * 128 + i];
    p[i]       = __float2bfloat16(x1 * c - x2 * sn);
    p[128 + i] = __float2bfloat16(x1 * sn + x2 * c);
}

// v rows (stride ldv, base already offset to v region) -> vT (NKV, HD, S) bf16
__global__ void transpose_v_kernel(const __hip_bfloat16* __restrict__ v,
                                   __hip_bfloat16* __restrict__ vt, int ldv) {
    __shared__ ushort tile[64][65];
    int s0 = blockIdx.x * 64, d0 = blockIdx.y * 64, kv = blockIdx.z;
    const ushort* vin = (const ushort*)v;
    ushort* vout = (ushort*)vt;
    #pragma unroll
    for (int it = 0; it < 4; ++it) {
        int slot = it * 256 + threadIdx.x;
        int r = slot >> 4, c4 = (slot & 15) << 2;
        ushort4 x = *(const ushort4*)(vin + (long)(s0 + r) * ldv + kv * HD + d0 + c4);
        tile[r][c4] = x.x; tile[r][c4 + 1] = x.y; tile[r][c4 + 2] = x.z; tile[r][c4 + 3] = x.w;
    }
    __syncthreads();
    #pragma unroll
    for (int it = 0; it < 4; ++it) {
        int slot = it * 256 + threadIdx.x;
        int rr = slot >> 4, c4 = (slot & 15) << 2;
        ushort4 y;
        y.x = tile[c4][rr]; y.y = tile[c4 + 1][rr]; y.z = tile[c4 + 2][rr]; y.w = tile[c4 + 3][rr];
        *(ushort4*)(vout + (long)kv * HD * S + (long)(d0 + rr) * S + s0 + c4) = y;
    }
}

// scores (NH,S,S) bf16 -> probs bf16, with scale, tanh softcap, mask, softmax.
__global__ void softmax_kernel(const __hip_bfloat16* __restrict__ sc,
                               __hip_bfloat16* __restrict__ pr, int isLocal) {
    int i = blockIdx.x, hh = blockIdx.y;
    const __hip_bfloat16* row = sc + ((long)hh * S + i) * S;
    __hip_bfloat16* orow = pr + ((long)hh * S + i) * S;
    int lo = isLocal ? max(0, i - (WINDOW - 1)) : 0;
    float vals[8];
    float m = -3.0e38f;
    #pragma unroll
    for (int t = 0; t < 8; ++t) {
        int j = t * 256 + threadIdx.x;
        bool chunkAny = (t * 256 <= i) && (t * 256 + 255 >= lo);
        if (chunkAny) {
            bool valid = (j <= i) && (j >= lo);
            float v = tanhf(__bfloat162float(row[j]) * (0.0625f / 50.f)) * 50.f;
            vals[t] = valid ? v : -3.0e38f;
            m = fmaxf(m, vals[t]);
        } else {
            vals[t] = -3.0e38f;
        }
    }
    m = blk_max(m);
    float ps[8], ssum = 0.f;
    #pragma unroll
    for (int t = 0; t < 8; ++t) {
        float p = (vals[t] > -1.0e38f) ? __expf(vals[t] - m) : 0.f;
        ps[t] = p; ssum += p;
    }
    ssum = blk_sum(ssum);
    float inv = 1.f / ssum;
    #pragma unroll
    for (int t = 0; t < 8; ++t) {
        int j = t * 256 + threadIdx.x;
        orow[j] = __float2bfloat16(ps[t] * inv);
    }
}

// gate half *= up half, packed gu[S][16384] (fallback path only)
__global__ void mul_gu_kernel(__hip_bfloat16* __restrict__ gu) {
    long idx = ((long)blockIdx.x * 256 + threadIdx.x) * 8;
    long s = idx >> 13;
    long f = idx & 8191;
    __hip_bfloat16* gp = gu + s * 16384 + f;
    const __hip_bfloat16* up = gu + s * 16384 + 8192 + f;
    uint4 gv = *(const uint4*)gp;
    uint4 uv = *(const uint4*)up;
    const __hip_bfloat16* gb = (const __hip_bfloat16*)&gv;
    const __hip_bfloat16* ub = (const __hip_bfloat16*)&uv;
    __hip_bfloat16 o[8];
    #pragma unroll
    for (int j = 0; j < 8; ++j)
        o[j] = __float2bfloat16(__bfloat162float(gb[j]) * __bfloat162float(ub[j]));
    *(uint4*)gp = *(const uint4*)o;
}

// ---------------- generic pipelined GEMM: C[M,N] = A[M,K] * B[N,K]^T, bf16 ----------------
// Tile BM=WM*MI*16 x BN=WN*NI*16, BK=32, threads T=WM*WN*64 (BM==BN==T/2 required by staging).
// 4 LDS buffers, depth-3 prefetch, 2 sub-phases/K-tile, counted vmcnt(8), setprio around MFMA,
// both-sides XOR swizzle, XCD-chunked 1-D grid remap (nwg % 8 == 0).
// EPI: 0=f32, 1=bf16, 3=tanh(x/30)*30->f32,
//      5=interleaved gelu(gate)*up -> bf16 (B rows interleaved wg/wu; even lanes write f=col/2)
// kMode: 0 none; 1 causal score-tile skip; 2 local score-tile skip; 3 causal PV K-range; 4 local PV K-range
template<int EPI, int WM, int WN, int MI, int NI>
__global__ __launch_bounds__(WM*WN*64, 2) void gemm_pipe(
    const __hip_bfloat16* __restrict__ A, const __hip_bfloat16* __restrict__ B,
    void* __restrict__ Cv, int K, int lda, int ldb, int ldc,
    long aBatch, long bBatch, long cBatch, int bzDiv, int gx, int kMode) {
    constexpr int T  = WM * WN * 64;
    constexpr int BM = WM * MI * 16;
    constexpr int BN = WN * NI * 16;
    constexpr int AE = BM * 32;
    constexpr int BE = BN * 32;
    __shared__ __hip_bfloat16 lds[4][AE + BE];

    const int tid = threadIdx.x;
    const int nwg = gridDim.x;
    const int orig = blockIdx.x;
    const int wgid = (orig & 7) * (nwg >> 3) + (orig >> 3);
    const int bx = wgid % gx, by = wgid / gx;
    const int bz = blockIdx.z;

    int kstart = 0, kend = K;
    if (kMode == 1) { if (by > bx) return; }
    else if (kMode == 2) { if (by > bx || bx - by >= 9) return; }
    else if (kMode == 3) { kend = min(K, (bx + 1) * BM); }
    else if (kMode == 4) { kend = min(K, (bx + 1) * BM); kstart = max(0, (bx - 1024 / BM) * BM); }

    const __hip_bfloat16* Ab = A + (long)bz * aBatch + (long)bx * BM * lda;
    const __hip_bfloat16* Bb = B + (long)(bz / bzDiv) * bBatch + (long)by * BN * ldb;

    const int w = tid >> 6, l = tid & 63;
    const int wm = w / WN, wn = w % WN;
    const int wrow = wm * MI * 16, wcol = wn * NI * 16;
    const int fr = l & 15, g = l >> 4;
    const int sR = tid >> 2;
    const int sc = tid & 3;

    floatx4 acc[MI][NI] = {};
    bf16x8 bfv[NI];
    bf16x8 af[MI / 2];

    auto stageA = [&](int t, int buf) {
        const int k0 = kstart + t * 32;
        #pragma unroll
        for (int i = 0; i < 2; ++i) {
            int row = sR + i * (T / 4);
            int scol = ((sc ^ ((row >> 1) & 3)) << 3);
            __builtin_amdgcn_global_load_lds(
                (kGlb*)(Ab + (long)row * lda + k0 + scol),
                (kLds*)(&lds[buf][0] + tid * 8 + i * (T * 8)), 16, 0, 0);
        }
    };
    auto stageB = [&](int t, int buf) {
        const int k0 = kstart + t * 32;
        #pragma unroll
        for (int i = 0; i < 2; ++i) {
            int row = sR + i * (T / 4);
            int scol = ((sc ^ ((row >> 1) & 3)) << 3);
            __builtin_amdgcn_global_load_lds(
                (kGlb*)(Bb + (long)row * ldb + k0 + scol),
                (kLds*)(&lds[buf][AE] + tid * 8 + i * (T * 8)), 16, 0, 0);
        }
    };

    auto phase0 = [&](int buf, int t3, bool doStage) {
        const char* AsB = (const char*)&lds[buf][0];
        const char* BsB = (const char*)&lds[buf][AE];
        #pragma unroll
        for (int mi = 0; mi < MI / 2; ++mi) {
            int ra = wrow + mi * 16 + fr;
            af[mi] = *(const bf16x8*)(AsB + ra * 64 + ((g ^ ((ra >> 1) & 3)) << 4));
        }
        #pragma unroll
        for (int ni = 0; ni < NI; ++ni) {
            int rb = wcol + ni * 16 + fr;
            bfv[ni] = *(const bf16x8*)(BsB + rb * 64 + ((g ^ ((rb >> 1) & 3)) << 4));
        }
        if (doStage) stageA(t3, t3 & 3);
        __builtin_amdgcn_s_barrier();
        asm volatile("s_waitcnt lgkmcnt(0)" ::: "memory");
        __builtin_amdgcn_sched_barrier(0);
        __builtin_amdgcn_s_setprio(1);
        #pragma unroll
        for (int mi = 0; mi < MI / 2; ++mi)
            #pragma unroll
            for (int ni = 0; ni < NI; ++ni)
                acc[mi][ni] = __builtin_amdgcn_mfma_f32_16x16x32_bf16(af[mi], bfv[ni], acc[mi][ni], 0, 0, 0);
        __builtin_amdgcn_s_setprio(0);
        __builtin_amdgcn_sched_barrier(0);
        __builtin_amdgcn_s_barrier();
    };

    auto phase1 = [&](int buf, int t3, bool doStage, int vm) {
        const char* AsB = (const char*)&lds[buf][0];
        #pragma unroll
        for (int mi = 0; mi < MI / 2; ++mi) {
            int ra = wrow + (MI / 2 + mi) * 16 + fr;
            af[mi] = *(const bf16x8*)(AsB + ra * 64 + ((g ^ ((ra >> 1) & 3)) << 4));
        }
        if (doStage) stageB(t3, t3 & 3);
        if (vm == 8)      asm volatile("s_waitcnt vmcnt(8)" ::: "memory");
        else if (vm == 4) asm volatile("s_waitcnt vmcnt(4)" ::: "memory");
        else if (vm == 0) asm volatile("s_waitcnt vmcnt(0)" ::: "memory");
        __builtin_amdgcn_s_barrier();
        asm volatile("s_waitcnt lgkmcnt(0)" ::: "memory");
        __builtin_amdgcn_sched_barrier(0);
        __builtin_amdgcn_s_setprio(1);
        #pragma unroll
        for (int mi = 0; mi < MI / 2; ++mi)
            #pragma unroll
            for (int ni = 0; ni < NI; ++ni)
                acc[MI / 2 + mi][ni] = __builtin_amdgcn_mfma_f32_16x16x32_bf16(af[mi], bfv[ni], acc[MI / 2 + mi][ni], 0, 0, 0);
        __builtin_amdgcn_s_setprio(0);
        __builtin_amdgcn_sched_barrier(0);
        __builtin_amdgcn_s_barrier();
    };

    const int nt = (kend - kstart) >> 5;
    stageA(0, 0); stageB(0, 0);
    stageA(1, 1); stageB(1, 1);
    stageA(2, 2); stageB(2, 2);
    asm volatile("s_waitcnt vmcnt(8)" ::: "memory");
    __builtin_amdgcn_s_barrier();

    for (int t = 0; t < nt - 3; ++t) {
        const int b = t & 3;
        phase0(b, t + 3, true);
        phase1(b, t + 3, true, 8);
    }
    phase0((nt - 3) & 3, 0, false); phase1((nt - 3) & 3, 0, false, 4);
    phase0((nt - 2) & 3, 0, false); phase1((nt - 2) & 3, 0, false, 0);
    phase0((nt - 1) & 3, 0, false); phase1((nt - 1) & 3, 0, false, -1);

    const long cBase = (long)bz * cBatch + (long)bx * BM * ldc + (long)by * BN;
    const int rg = (l >> 4) * 4;
    #pragma unroll
    for (int mi = 0; mi < MI; ++mi) {
        #pragma unroll
        for (int ni = 0; ni < NI; ++ni) {
            #pragma unroll
            for (int r = 0; r < 4; ++r) {
                int row = wrow + mi * 16 + rg + r;
                int col = wcol + ni * 16 + fr;
                float v = acc[mi][ni][r];
                if constexpr (EPI == 5) {
                    // B rows interleaved: even col = gate (wg), odd col = up (wu).
                    float pv = __shfl_xor(v, 1);   // partner lane: same row, col^1
                    if (!(fr & 1)) {
                        float gg = 0.5f * v * (1.f + tanhf(0.7978845608f * (v + 0.044715f * v * v * v)));
                        long idx5 = ((long)bx * BM + row) * (long)ldc + (long)by * (BN / 2) + (col >> 1);
                        ((__hip_bfloat16*)Cv)[idx5] = __float2bfloat16(gg * pv);
                    }
                } else {
                    long idx = cBase + (long)row * ldc + col;
                    if constexpr (EPI == 0) {
                        ((float*)Cv)[idx] = v;
                    } else if constexpr (EPI == 1) {
                        ((__hip_bfloat16*)Cv)[idx] = __float2bfloat16(v);
                    } else if constexpr (EPI == 3) {
                        ((float*)Cv)[idx] = tanhf(v * (1.f / 30.f)) * 30.f;
                    }
                }
            }
        }
    }
}

// ---------------- fallback GEMM with fp32 B staging (used only if ws too small) ----------------
template<int EPI>
__global__ __launch_bounds__(256) void gemm_f32w(
    const __hip_bfloat16* __restrict__ A, const float* __restrict__ Bv,
    void* __restrict__ Cv, int K, int lda, int ldb, int ldc) {
    __shared__ __hip_bfloat16 As[128][32];
    __shared__ __hip_bfloat16 Bs[128][32];
    const int tid = threadIdx.x;
    const __hip_bfloat16* Ab = A + (long)blockIdx.x * 128 * lda;
    const float* Bb = Bv + (long)blockIdx.y * 128 * ldb;
    const int wid = tid >> 6, lane = tid & 63;
    const int wr = (wid >> 1) * 64, wc = (wid & 1) * 64;
    const int fr = lane & 15;
    const int kb = (lane >> 4) * 8;
    floatx4 acc[4][4] = {};
    for (int k0 = 0; k0 < K; k0 += 32) {
        __syncthreads();
        #pragma unroll
        for (int it = 0; it < 2; ++it) {
            int slot = tid + it * 256;
            int r = slot >> 2, c8 = (slot & 3) * 8;
            *reinterpret_cast<uint4*>(&As[r][c8]) =
                *reinterpret_cast<const uint4*>(Ab + (long)r * lda + k0 + c8);
        }
        #pragma unroll
        for (int it = 0; it < 4; ++it) {
            int slot = tid + it * 256;
            int r = slot >> 3, c4 = (slot & 7) * 4;
            float4 f = *reinterpret_cast<const float4*>(Bb + (long)r * ldb + k0 + c4);
            __hip_bfloat16 t4[4] = {__float2bfloat16(f.x), __float2bfloat16(f.y),
                                    __float2bfloat16(f.z), __float2bfloat16(f.w)};
            *reinterpret_cast<ushort4*>(&Bs[r][c4]) = *reinterpret_cast<const ushort4*>(t4);
        }
        __syncthreads();
        bf16x8 af[4], bfr[4];
        #pragma unroll
        for (int i = 0; i < 4; ++i)
            af[i] = *reinterpret_cast<const bf16x8*>(&As[wr + i * 16 + fr][kb]);
        #pragma unroll
        for (int j = 0; j < 4; ++j)
            bfr[j] = *reinterpret_cast<const bf16x8*>(&Bs[wc + j * 16 + fr][kb]);
        #pragma unroll
        for (int i = 0; i < 4; ++i)
            #pragma unroll
            for (int j = 0; j < 4; ++j)
                acc[i][j] = __builtin_amdgcn_mfma_f32_16x16x32_bf16(af[i], bfr[j], acc[i][j], 0, 0, 0);
    }
    const long cTile = (long)blockIdx.x * 128 * ldc + (long)blockIdx.y * 128;
    const int rg = (lane >> 4) * 4;
    #pragma unroll
    for (int i = 0; i < 4; ++i)
        #pragma unroll
        for (int j = 0; j < 4; ++j)
            #pragma unroll
            for (int r = 0; r < 4; ++r) {
                int row = wr + i * 16 + rg + r;
                int col = wc + j * 16 + fr;
                long idx = cTile + (long)row * ldc + col;
                float v = acc[i][j][r];
                if constexpr (EPI == 0) ((float*)Cv)[idx] = v;
                else if constexpr (EPI == 1) ((__hip_bfloat16*)Cv)[idx] = __float2bfloat16(v);
                else if constexpr (EPI == 2) {
                    float gg = 0.5f * v * (1.f + tanhf(0.7978845608f * (v + 0.044715f * v * v * v)));
                    ((__hip_bfloat16*)Cv)[idx] = __float2bfloat16(gg);
                } else ((float*)Cv)[idx] = tanhf(v * (1.f / 30.f)) * 30.f;
            }
}

// ---------------- host ----------------
extern "C" void kernel_launch(void* const* d_in, const int* in_sizes, int n_in,
                              void* d_out, int out_size, void* d_ws, size_t ws_size,
                              hipStream_t stream) {
    const int*   ids    = (const int*)d_in[0];
    const float* embedW = (const float*)d_in[1];
    const float* wq     = (const float*)d_in[2];
    const float* wk     = (const float*)d_in[3];
    const float* wv     = (const float*)d_in[4];
    const float* wo     = (const float*)d_in[5];
    const float* wg     = (const float*)d_in[6];
    const float* wu     = (const float*)d_in[7];
    const float* wd     = (const float*)d_in[8];
    const float* ln_in  = (const float*)d_in[9];
    const float* ln_pa  = (const float*)d_in[10];
    const float* ln_pf  = (const float*)d_in[11];
    const float* ln_pff = (const float*)d_in[12];
    const float* ln_f   = (const float*)d_in[13];
    const float* w_lm   = (const float*)d_in[14];
    float* out = (float*)d_out;

    char* ws = (char*)d_ws;
    size_t off = 0;
    auto alloc = [&](size_t bytes) -> void* {
        size_t o = (off + 255) & ~(size_t)255;
        off = o + bytes;
        return (void*)(ws + o);
    };

    float* h            = (float*)alloc((size_t)S * D * 4);
    __hip_bfloat16* xb  = (__hip_bfloat16*)alloc((size_t)S * D * 2);
    __hip_bfloat16* qkvb = (__hip_bfloat16*)alloc((size_t)S * 4096 * 2); // q|k|v packed
    __hip_bfloat16* vT  = (__hip_bfloat16*)alloc((size_t)NKV * HD * S * 2);
    __hip_bfloat16* ab  = (__hip_bfloat16*)alloc((size_t)S * NH * HD * 2);
    float* tmpf         = (float*)alloc((size_t)S * D * 4);
    __hip_bfloat16* guP = (__hip_bfloat16*)alloc((size_t)S * FF * 2);    // gelu(gate)*up
    __hip_bfloat16* gu  = (__hip_bfloat16*)alloc((size_t)S * 16384 * 2); // fallback only
    float* cosb         = (float*)alloc((size_t)S * 128 * 4);
    float* sinb         = (float*)alloc((size_t)S * 128 * 4);
    __hip_bfloat16* scores = (__hip_bfloat16*)alloc((size_t)NH * S * S * 2);
    __hip_bfloat16* probs  = (__hip_bfloat16*)alloc((size_t)NH * S * S * 2);

    const long SLq = 2048L * 2048, SLkv = 1024L * 2048, SLff = 8192L * 2048;
    const long nWlm = (long)VOCAB * D;
    __hip_bfloat16* wqkvb = (__hip_bfloat16*)alloc(4L * 4096 * 2048 * 2);
    __hip_bfloat16* wgub  = (__hip_bfloat16*)alloc(4L * 16384 * 2048 * 2); // interleaved wg/wu
    __hip_bfloat16* wob   = (__hip_bfloat16*)alloc(4L * SLq * 2);
    __hip_bfloat16* wdb   = (__hip_bfloat16*)alloc(4L * SLff * 2);
    __hip_bfloat16* wlmb  = (__hip_bfloat16*)alloc(nWlm * 2);
    const bool big = (off <= ws_size);
    (void)in_sizes; (void)n_in; (void)out_size;

    rope_table_kernel<<<dim3(S), dim3(128), 0, stream>>>(cosb, sinb);
    embed_kernel<<<dim3(D / 256, S), dim3(256), 0, stream>>>(ids, embedW, h);

    auto cvt = [&](const float* s, __hip_bfloat16* dp, long n) {
        long n8 = n / 8;
        long want = (n8 + 255) / 256;
        int blocks = (int)(want < 2048 ? want : 2048);
        cvt_bf16_kernel<<<dim3(blocks), dim3(256), 0, stream>>>(s, dp, n8);
    };
    auto cvtI = [&](const float* s, __hip_bfloat16* dp, int half, long n) {
        long n8 = n / 8;
        long want = (n8 + 255) / 256;
        int blocks = (int)(want < 2048 ? want : 2048);
        cvt_inter_kernel<<<dim3(blocks), dim3(256), 0, stream>>>(s, dp, half, n8);
    };
    if (big) {
        for (int l = 0; l < NLAYER; ++l) {
            cvt(wq + l * SLq,  wqkvb + (size_t)l * 4096 * 2048,                SLq);
            cvt(wk + l * SLkv, wqkvb + (size_t)l * 4096 * 2048 + 2048L * 2048, SLkv);
            cvt(wv + l * SLkv, wqkvb + (size_t)l * 4096 * 2048 + 3072L * 2048, SLkv);
            cvtI(wg + l * SLff, wgub + (size_t)l * 16384 * 2048, 0, SLff);
            cvtI(wu + l * SLff, wgub + (size_t)l * 16384 * 2048, 1, SLff);
        }
        cvt(wo, wob, 4L * SLq);
        cvt(wd, wdb, 4L * SLff);
        cvt(w_lm, wlmb, nWlm);
    }

    // launchers: p256 = 256x256 (512 thr), p128 = 128x128 (256 thr)
    auto p256 = [&](int epi, const __hip_bfloat16* A, const __hip_bfloat16* B, void* C,
                    int K, int lda, int ldb, int ldc, int gx, int gy) {
        dim3 grid(gx * gy, 1, 1);
        if (epi == 3)
            gemm_pipe<3, 2, 4, 8, 4><<<grid, 512, 0, stream>>>(A, B, C, K, lda, ldb, ldc, 0, 0, 0, 1, gx, 0);
        else
            gemm_pipe<5, 2, 4, 8, 4><<<grid, 512, 0, stream>>>(A, B, C, K, lda, ldb, ldc, 0, 0, 0, 1, gx, 0);
    };
    auto p128 = [&](int epi, const __hip_bfloat16* A, const __hip_bfloat16* B, void* C,
                    int K, int lda, int ldb, int ldc, int gx, int gy, int gz,
                    long aB, long bB, long cB, int bzDiv, int kMode) {
        dim3 grid(gx * gy, 1, gz);
        switch (epi) {
        case 0: gemm_pipe<0, 2, 2, 4, 4><<<grid, 256, 0, stream>>>(A, B, C, K, lda, ldb, ldc, aB, bB, cB, bzDiv, gx, kMode); break;
        default: gemm_pipe<1, 2, 2, 4, 4><<<grid, 256, 0, stream>>>(A, B, C, K, lda, ldb, ldc, aB, bB, cB, bzDiv, gx, kMode); break;
        }
    };

    for (int l = 0; l < NLAYER; ++l) {
        int isLocal = (l % 2 == 0) ? 1 : 0;
        rms_bf16_kernel<<<dim3(S), dim3(256), 0, stream>>>(h, ln_in + l * D, xb);
        if (big) {
            p128(1, xb, wqkvb + (size_t)l * 4096 * 2048, qkvb, D, D, D, 4096, 16, 32, 1, 0, 0, 0, 1, 0);
        } else {
            gemm_f32w<1><<<dim3(16, 16), 256, 0, stream>>>(xb, wq + l * SLq, qkvb, D, D, D, 4096);
            gemm_f32w<1><<<dim3(16, 8), 256, 0, stream>>>(xb, wk + l * SLkv, qkvb + 2048, D, D, D, 4096);
            gemm_f32w<1><<<dim3(16, 8), 256, 0, stream>>>(xb, wv + l * SLkv, qkvb + 3072, D, D, D, 4096);
        }
        rope_kernel<<<dim3(S, NH), dim3(128), 0, stream>>>(qkvb, cosb, sinb, 4096);
        rope_kernel<<<dim3(S, NKV), dim3(128), 0, stream>>>(qkvb + 2048, cosb, sinb, 4096);
        transpose_v_kernel<<<dim3(S / 64, HD / 64, NKV), 256, 0, stream>>>(qkvb + 3072, vT, 4096);
        // scores = q @ k^T per head (bf16 out), masked-tile skip
        p128(1, qkvb, qkvb + 2048, scores, HD, 4096, 4096, S, 16, 16, NH,
             (long)HD, (long)HD, (long)S * S, 2, isLocal ? 2 : 1);
        softmax_kernel<<<dim3(S, NH), dim3(256), 0, stream>>>(scores, probs, isLocal);
        // a = probs @ vT, K-range restricted to valid band
        p128(1, probs, vT, ab, S, S, S, NH * HD, 16, 2, NH,
             (long)S * S, (long)HD * S, (long)HD, 2, isLocal ? 4 : 3);
        if (big) {
            p128(0, ab, wob + (size_t)l * SLq, tmpf, NH * HD, NH * HD, NH * HD, D, 16, 16, 1, 0, 0, 0, 1, 0);
        } else {
            gemm_f32w<0><<<dim3(16, 16), 256, 0, stream>>>(ab, wo + l * SLq, tmpf, NH * HD, NH * HD, NH * HD, D);
        }
        resid_rms_kernel<<<dim3(S), dim3(256), 0, stream>>>(h, tmpf, ln_pa + l * D);
        rms_bf16_kernel<<<dim3(S), dim3(256), 0, stream>>>(h, ln_pf + l * D, xb);
        if (big) {
            // fused gate|up with interleaved rows; epilogue writes gelu(gate)*up -> guP [S][8192]
            p256(5, xb, wgub + (size_t)l * 16384 * 2048, guP, D, D, D, FF, 8, 64);
        } else {
            gemm_f32w<2><<<dim3(16, 64), 256, 0, stream>>>(xb, wg + l * SLff, gu, D, D, D, 16384);
            gemm_f32w<1><<<dim3(16, 64), 256, 0, stream>>>(xb, wu + l * SLff, gu + 8192, D, D, D, 16384);
            mul_gu_kernel<<<dim3((S * FF) / (256 * 8)), 256, 0, stream>>>(gu);
        }
        if (big) {
            p128(0, guP, wdb + (size_t)l * SLff, tmpf, FF, FF, FF, D, 16, 16, 1, 0, 0, 0, 1, 0);
        } else {
            gemm_f32w<0><<<dim3(16, 16), 256, 0, stream>>>(gu, wd + l * SLff, tmpf, FF, 16384, FF, D);
        }
        resid_rms_kernel<<<dim3(S), dim3(256), 0, stream>>>(h, tmpf, ln_pff + l * D);
    }

    rms_bf16_kernel<<<dim3(S), dim3(256), 0, stream>>>(h, ln_f, xb);
    if (big) {
        p256(3, xb, wlmb, out, D, D, D, VOCAB, 8, VOCAB / 256);
    } else {
        gemm_f32w<3><<<dim3(16, VOCAB / 128), 256, 0, stream>>>(xb, w_lm, out, D, D, D, VOCAB);
    }
}

// Round 8
// 2572.554 us; speedup vs baseline: 1.0745x; 1.0081x over previous
//
#include <hip/hip_runtime.h>
#include <hip/hip_bf16.h>

typedef __attribute__((ext_vector_type(8))) __bf16 bf16x8;
typedef __attribute__((ext_vector_type(4))) float floatx4;

typedef __attribute__((address_space(1))) const unsigned char kGlb;
typedef __attribute__((address_space(3))) unsigned char kLds;

static constexpr int S = 2048;
static constexpr int D = 2048;
static constexpr int HD = 256;
static constexpr int NH = 8;
static constexpr int NKV = 4;
static constexpr int NLAYER = 4;
static constexpr int VOCAB = 32000;
static constexpr int FF = 8192;
static constexpr int WINDOW = 1024;

// ---------------- block reduction helpers (256 threads = 4 waves) ----------------
__device__ __forceinline__ float blk_sum(float v) {
    __shared__ float sm[4];
    #pragma unroll
    for (int o = 32; o > 0; o >>= 1) v += __shfl_down(v, o, 64);
    int lane = threadIdx.x & 63, w = threadIdx.x >> 6;
    __syncthreads();
    if (lane == 0) sm[w] = v;
    __syncthreads();
    return sm[0] + sm[1] + sm[2] + sm[3];
}

__device__ __forceinline__ float blk_max(float v) {
    __shared__ float sm[4];
    #pragma unroll
    for (int o = 32; o > 0; o >>= 1) v = fmaxf(v, __shfl_down(v, o, 64));
    int lane = threadIdx.x & 63, w = threadIdx.x >> 6;
    __syncthreads();
    if (lane == 0) sm[w] = v;
    __syncthreads();
    return fmaxf(fmaxf(sm[0], sm[1]), fmaxf(sm[2], sm[3]));
}

// ---------------- elementwise kernels ----------------
__global__ void embed_kernel(const int* __restrict__ ids, const float* __restrict__ E,
                             float* __restrict__ h) {
    int d = blockIdx.x * 256 + threadIdx.x;
    int s = blockIdx.y;
    h[(long)s * D + d] = E[(long)ids[s] * D + d] * 45.25483399593904f; // sqrt(2048)
}

__global__ void rope_table_kernel(float* __restrict__ c, float* __restrict__ sn) {
    int i = threadIdx.x;   // 0..127
    int p = blockIdx.x;    // 0..S-1
    float inv = powf(10000.f, -(float)i / 128.f);
    float a = (float)p * inv;
    c[p * 128 + i] = cosf(a);
    sn[p * 128 + i] = sinf(a);
}

// fp32 -> bf16 conversion (grid-stride, 8 elems/thread/iter)
__global__ void cvt_bf16_kernel(const float* __restrict__ src, __hip_bfloat16* __restrict__ dst,
                                long n8) {
    long stride = (long)gridDim.x * 256;
    for (long i = (long)blockIdx.x * 256 + threadIdx.x; i < n8; i += stride) {
        long o = i * 8;
        float4 a = *(const float4*)(src + o);
        float4 b = *(const float4*)(src + o + 4);
        __hip_bfloat16 h8[8] = {
            __float2bfloat16(a.x), __float2bfloat16(a.y),
            __float2bfloat16(a.z), __float2bfloat16(a.w),
            __float2bfloat16(b.x), __float2bfloat16(b.y),
            __float2bfloat16(b.z), __float2bfloat16(b.w)};
        *(uint4*)(dst + o) = *(const uint4*)h8;
    }
}

// fp32 (rows x 2048) -> bf16 at interleaved rows: dst row = 2*row + half
__global__ void cvt_inter_kernel(const float* __restrict__ src, __hip_bfloat16* __restrict__ dst,
                                 int half, long n8) {
    long stride = (long)gridDim.x * 256;
    for (long i = (long)blockIdx.x * 256 + threadIdx.x; i < n8; i += stride) {
        long o = i * 8;
        long row = o >> 11, col = o & 2047;
        float4 a = *(const float4*)(src + o);
        float4 b = *(const float4*)(src + o + 4);
        __hip_bfloat16 h8[8] = {
            __float2bfloat16(a.x), __float2bfloat16(a.y),
            __float2bfloat16(a.z), __float2bfloat16(a.w),
            __float2bfloat16(b.x), __float2bfloat16(b.y),
            __float2bfloat16(b.z), __float2bfloat16(b.w)};
        *(uint4*)(dst + ((row * 2 + half) << 11) + col) = *(const uint4*)h8;
    }
}

// x = rms(h, w) -> bf16
__global__ void rms_bf16_kernel(const float* __restrict__ h, const float* __restrict__ w,
                                __hip_bfloat16* __restrict__ o) {
    int s = blockIdx.x;
    const float* row = h + (long)s * D;
    float vals[8], ss = 0.f;
    #pragma unroll
    for (int t = 0; t < 8; ++t) {
        int j = t * 256 + threadIdx.x;
        float v = row[j]; vals[t] = v; ss += v * v;
    }
    ss = blk_sum(ss);
    float r = rsqrtf(ss * (1.f / D) + 1e-6f);
    #pragma unroll
    for (int t = 0; t < 8; ++t) {
        int j = t * 256 + threadIdx.x;
        o[(long)s * D + j] = __float2bfloat16(vals[t] * r * (1.f + w[j]));
    }
}

// h += rms(t, w)
__global__ void resid_rms_kernel(float* __restrict__ h, const float* __restrict__ tt,
                                 const float* __restrict__ w) {
    int s = blockIdx.x;
    const float* row = tt + (long)s * D;
    float* hr = h + (long)s * D;
    float vals[8], ss = 0.f;
    #pragma unroll
    for (int t = 0; t < 8; ++t) {
        int j = t * 256 + threadIdx.x;
        float v = row[j]; vals[t] = v; ss += v * v;
    }
    ss = blk_sum(ss);
    float r = rsqrtf(ss * (1.f / D) + 1e-6f);
    #pragma unroll
    for (int t = 0; t < 8; ++t) {
        int j = t * 256 + threadIdx.x;
        hr[j] += vals[t] * r * (1.f + w[j]);
    }
}

// in-place RoPE on rows with stride ldx; head offset hh*HD; 128 threads per (s, head)
__global__ void rope_kernel(__hip_bfloat16* __restrict__ x, const float* __restrict__ cb,
                            const float* __restrict__ sb, int ldx) {
    int s = blockIdx.x, hh = blockIdx.y, i = threadIdx.x; // i in 0..127
    __hip_bfloat16* p = x + (long)s * ldx + hh * HD;
    float x1 = __bfloat162float(p[i]);
    float x2 = __bfloat162float(p[128 + i]);
    float c = cb[s * 128 + i], sn = sb[s * 128 + i];
    p[i]       = __float2bfloat16(x1 * c - x2 * sn);
    p[128 + i] = __float2bfloat16(x1 * sn + x2 * c);
}

// v rows (stride ldv) -> vT (NKV, HD, S) bf16
__global__ void transpose_v_kernel(const __hip_bfloat16* __restrict__ v,
                                   __hip_bfloat16* __restrict__ vt, int ldv) {
    __shared__ ushort tile[64][65];
    int s0 = blockIdx.x * 64, d0 = blockIdx.y * 64, kv = blockIdx.z;
    const ushort* vin = (const ushort*)v;
    ushort* vout = (ushort*)vt;
    #pragma unroll
    for (int it = 0; it < 4; ++it) {
        int slot = it * 256 + threadIdx.x;
        int r = slot >> 4, c4 = (slot & 15) << 2;
        ushort4 x = *(const ushort4*)(vin + (long)(s0 + r) * ldv + kv * HD + d0 + c4);
        tile[r][c4] = x.x; tile[r][c4 + 1] = x.y; tile[r][c4 + 2] = x.z; tile[r][c4 + 3] = x.w;
    }
    __syncthreads();
    #pragma unroll
    for (int it = 0; it < 4; ++it) {
        int slot = it * 256 + threadIdx.x;
        int rr = slot >> 4, c4 = (slot & 15) << 2;
        ushort4 y;
        y.x = tile[c4][rr]; y.y = tile[c4 + 1][rr]; y.z = tile[c4 + 2][rr]; y.w = tile[c4 + 3][rr];
        *(ushort4*)(vout + (long)kv * HD * S + (long)(d0 + rr) * S + s0 + c4) = y;
    }
}

// scores (NH,S,S) bf16 -> probs bf16, with scale, tanh softcap, mask, softmax.
__global__ void softmax_kernel(const __hip_bfloat16* __restrict__ sc,
                               __hip_bfloat16* __restrict__ pr, int isLocal) {
    int i = blockIdx.x, hh = blockIdx.y;
    const __hip_bfloat16* row = sc + ((long)hh * S + i) * S;
    __hip_bfloat16* orow = pr + ((long)hh * S + i) * S;
    int lo = isLocal ? max(0, i - (WINDOW - 1)) : 0;
    float vals[8];
    float m = -3.0e38f;
    #pragma unroll
    for (int t = 0; t < 8; ++t) {
        int j = t * 256 + threadIdx.x;
        bool chunkAny = (t * 256 <= i) && (t * 256 + 255 >= lo);
        if (chunkAny) {
            bool valid = (j <= i) && (j >= lo);
            float v = tanhf(__bfloat162float(row[j]) * (0.0625f / 50.f)) * 50.f;
            vals[t] = valid ? v : -3.0e38f;
            m = fmaxf(m, vals[t]);
        } else {
            vals[t] = -3.0e38f;
        }
    }
    m = blk_max(m);
    float ps[8], ssum = 0.f;
    #pragma unroll
    for (int t = 0; t < 8; ++t) {
        float p = (vals[t] > -1.0e38f) ? __expf(vals[t] - m) : 0.f;
        ps[t] = p; ssum += p;
    }
    ssum = blk_sum(ssum);
    float inv = 1.f / ssum;
    #pragma unroll
    for (int t = 0; t < 8; ++t) {
        int j = t * 256 + threadIdx.x;
        orow[j] = __float2bfloat16(ps[t] * inv);
    }
}

// gate half *= up half, packed gu[S][16384] (fallback path only)
__global__ void mul_gu_kernel(__hip_bfloat16* __restrict__ gu) {
    long idx = ((long)blockIdx.x * 256 + threadIdx.x) * 8;
    long s = idx >> 13;
    long f = idx & 8191;
    __hip_bfloat16* gp = gu + s * 16384 + f;
    const __hip_bfloat16* up = gu + s * 16384 + 8192 + f;
    uint4 gv = *(const uint4*)gp;
    uint4 uv = *(const uint4*)up;
    const __hip_bfloat16* gb = (const __hip_bfloat16*)&gv;
    const __hip_bfloat16* ub = (const __hip_bfloat16*)&uv;
    __hip_bfloat16 o[8];
    #pragma unroll
    for (int j = 0; j < 8; ++j)
        o[j] = __float2bfloat16(__bfloat162float(gb[j]) * __bfloat162float(ub[j]));
    *(uint4*)gp = *(const uint4*)o;
}

// ================= m201-style 8-phase 256x256 GEMM: C = A[M,K] * B[N,K]^T =================
// BK=64, 8 waves (2Mx4N), even K-tiles -> buf0, odd -> buf1; 2 halves (128 rows) per operand
// per buffer (128 KiB LDS). Per phase: {ds_read new frags; stage ONE half-tile; barrier;
// lgkmcnt(0); setprio(1); 16 MFMA (one quadrant); setprio(0); barrier}. Counted vmcnt(4)
// only at ph3/ph7 ends (vmcnt(0) on peeled last iteration). Swizzle: 16B chunk c^=(row&7)
// within 128B rows, on BOTH gload source and ds_read.
// EPI: 3 = tanh(x/30)*30 -> f32 (LM head); 5 = interleaved gelu(gate)*up -> bf16.
#define RD_AF(BUF, HALF)                                                          \
    {                                                                             \
        const char* _p = (const char*)&ldsA[BUF][HALF][0];                        \
        _Pragma("unroll")                                                         \
        for (int mi = 0; mi < 4; ++mi) {                                          \
            int r = wm * 64 + mi * 16 + fr;                                       \
            _Pragma("unroll")                                                     \
            for (int ks = 0; ks < 2; ++ks) {                                      \
                int c = ks * 4 + g;                                               \
                af[mi][ks] = *(const bf16x8*)(_p + r * 128 + ((c ^ (r & 7)) << 4)); \
            }                                                                     \
        }                                                                         \
    }

#define RD_BF(DST, BUF, HALF)                                                     \
    {                                                                             \
        const char* _p = (const char*)&ldsB[BUF][HALF][0];                        \
        _Pragma("unroll")                                                         \
        for (int ni = 0; ni < 2; ++ni) {                                          \
            int r = wn * 32 + ni * 16 + fr;                                       \
            _Pragma("unroll")                                                     \
            for (int ks = 0; ks < 2; ++ks) {                                      \
                int c = ks * 4 + g;                                               \
                DST[ni][ks] = *(const bf16x8*)(_p + r * 128 + ((c ^ (r & 7)) << 4)); \
            }                                                                     \
        }                                                                         \
    }

#define MM(QM, QN, BF)                                                            \
    __builtin_amdgcn_s_setprio(1);                                                \
    _Pragma("unroll")                                                             \
    for (int mi = 0; mi < 4; ++mi)                                                \
        _Pragma("unroll")                                                         \
        for (int ni = 0; ni < 2; ++ni)                                            \
            _Pragma("unroll")                                                     \
            for (int ks = 0; ks < 2; ++ks)                                        \
                acc[QM][QN][mi][ni] = __builtin_amdgcn_mfma_f32_16x16x32_bf16(    \
                    af[mi][ks], BF[ni][ks], acc[QM][QN][mi][ni], 0, 0, 0);        \
    __builtin_amdgcn_s_setprio(0);

#define PH_TAIL                                                                   \
    __builtin_amdgcn_s_barrier();                                                 \
    asm volatile("s_waitcnt lgkmcnt(0)" ::: "memory");                            \
    __builtin_amdgcn_sched_barrier(0);

#define PH_END                                                                    \
    __builtin_amdgcn_sched_barrier(0);                                            \
    __builtin_amdgcn_s_barrier();

template<int EPI>
__global__ __launch_bounds__(512, 2) void gemm_8ph(
    const __hip_bfloat16* __restrict__ A, const __hip_bfloat16* __restrict__ B,
    void* __restrict__ Cv, int K, int lda, int ldb, int ldc, int gx) {
    __shared__ __hip_bfloat16 ldsA[2][2][8192];   // [buf][half][128*64]
    __shared__ __hip_bfloat16 ldsB[2][2][8192];
    const int tid = threadIdx.x;
    const int nwg = gridDim.x;
    const int orig = blockIdx.x;
    const int wgid = (orig & 7) * (nwg >> 3) + (orig >> 3);   // nwg % 8 == 0
    const int bx = wgid % gx, by = wgid / gx;

    const __hip_bfloat16* Ab = A + (long)bx * 256 * lda;
    const __hip_bfloat16* Bb = B + (long)by * 256 * ldb;

    const int w = tid >> 6, l = tid & 63;
    const int wm = w >> 2, wn = w & 3;   // 2 x 4 wave grid
    const int fr = l & 15, g = l >> 4;
    const int sRow0 = tid >> 3;
    const int sCh = tid & 7;

    floatx4 acc[2][2][4][2] = {};
    bf16x8 af[4][2], bf0[2][2], bf1[2][2];

    auto stage = [&](const __hip_bfloat16* src, int ld, int k0, __hip_bfloat16* dst) {
        #pragma unroll
        for (int i = 0; i < 2; ++i) {
            int row = sRow0 + i * 64;
            int cs = (sCh ^ (row & 7)) * 8;
            __builtin_amdgcn_global_load_lds(
                (kGlb*)(src + (long)row * ld + k0 + cs),
                (kLds*)((char*)dst + i * 8192 + tid * 16), 16, 0, 0);
        }
    };

    const int nt = K >> 6;      // even, >= 4 at all call sites
    const int niter = nt >> 1;

    // prologue: tile0 full (buf0) + tile1 halves A0,B0 (buf1) = 12 loads
    stage(Ab,             lda, 0,  &ldsA[0][0][0]);
    stage(Bb,             ldb, 0,  &ldsB[0][0][0]);
    stage(Ab + 128 * lda, lda, 0,  &ldsA[0][1][0]);
    stage(Bb + 128 * ldb, ldb, 0,  &ldsB[0][1][0]);
    stage(Ab,             lda, 64, &ldsA[1][0][0]);
    stage(Bb,             ldb, 64, &ldsB[1][0][0]);
    asm volatile("s_waitcnt vmcnt(4)" ::: "memory");
    __builtin_amdgcn_s_barrier();

    for (int it = 0; it < niter; ++it) {
        const int t = it * 2;
        const bool last = (it == niter - 1);
        const int kN1 = (t + 1) * 64;
        const int kN2 = (t + 2) * 64;
        const int kN3 = (t + 3) * 64;
        // ph0: quadrant (0,0) of tile t; stage A1(t+1)
        RD_AF(0, 0);
        RD_BF(bf0, 0, 0);
        stage(Ab + 128 * lda, lda, kN1, &ldsA[1][1][0]);
        PH_TAIL
        MM(0, 0, bf0)
        PH_END
        // ph1: (0,1); stage B1(t+1)
        RD_BF(bf1, 0, 1);
        stage(Bb + 128 * ldb, ldb, kN1, &ldsB[1][1][0]);
        PH_TAIL
        MM(0, 1, bf1)
        PH_END
        // ph2: (1,0); stage A0(t+2)
        RD_AF(0, 1);
        if (!last) stage(Ab, lda, kN2, &ldsA[0][0][0]);
        PH_TAIL
        MM(1, 0, bf0)
        PH_END
        // ph3: (1,1); stage B0(t+2); W1
        if (!last) stage(Bb, ldb, kN2, &ldsB[0][0][0]);
        MM(1, 1, bf1)
        __builtin_amdgcn_sched_barrier(0);
        if (last) { asm volatile("s_waitcnt vmcnt(0)" ::: "memory"); }
        else      { asm volatile("s_waitcnt vmcnt(4)" ::: "memory"); }
        __builtin_amdgcn_s_barrier();
        // ph4: (0,0) of tile t+1; stage A1(t+2)
        RD_AF(1, 0);
        RD_BF(bf0, 1, 0);
        if (!last) stage(Ab + 128 * lda, lda, kN2, &ldsA[0][1][0]);
        PH_TAIL
        MM(0, 0, bf0)
        PH_END
        // ph5: (0,1); stage B1(t+2)
        RD_BF(bf1, 1, 1);
        if (!last) stage(Bb + 128 * ldb, ldb, kN2, &ldsB[0][1][0]);
        PH_TAIL
        MM(0, 1, bf1)
        PH_END
        // ph6: (1,0); stage A0(t+3)
        RD_AF(1, 1);
        if (!last) stage(Ab, lda, kN3, &ldsA[1][0][0]);
        PH_TAIL
        MM(1, 0, bf0)
        PH_END
        // ph7: (1,1); stage B0(t+3); W2
        if (!last) stage(Bb, ldb, kN3, &ldsB[1][0][0]);
        MM(1, 1, bf1)
        __builtin_amdgcn_sched_barrier(0);
        if (!last) { asm volatile("s_waitcnt vmcnt(4)" ::: "memory"); }
        __builtin_amdgcn_s_barrier();
    }

    const long cBase = (long)bx * 256 * ldc + (long)by * 256;
    const int rg = (l >> 4) * 4;
    #pragma unroll
    for (int qm = 0; qm < 2; ++qm)
    #pragma unroll
    for (int qn = 0; qn < 2; ++qn)
    #pragma unroll
    for (int mi = 0; mi < 4; ++mi)
    #pragma unroll
    for (int ni = 0; ni < 2; ++ni)
    #pragma unroll
    for (int r = 0; r < 4; ++r) {
        int row = qm * 128 + wm * 64 + mi * 16 + rg + r;
        int col = qn * 128 + wn * 32 + ni * 16 + fr;
        float v = acc[qm][qn][mi][ni][r];
        if constexpr (EPI == 3) {
            ((float*)Cv)[cBase + (long)row * ldc + col] = tanhf(v * (1.f / 30.f)) * 30.f;
        } else { // EPI 5: B rows interleaved wg/wu; even col = gate, odd = up
            float pv = __shfl_xor(v, 1);
            if (!(fr & 1)) {
                float gg = 0.5f * v * (1.f + tanhf(0.7978845608f * (v + 0.044715f * v * v * v)));
                long idx5 = ((long)bx * 256 + row) * (long)ldc + (long)by * 128 + (col >> 1);
                ((__hip_bfloat16*)Cv)[idx5] = __float2bfloat16(gg * pv);
            }
        }
    }
}

// ---------------- generic pipelined GEMM (128x128 path, unchanged) ----------------
template<int EPI, int WM, int WN, int MI, int NI>
__global__ __launch_bounds__(WM*WN*64, 2) void gemm_pipe(
    const __hip_bfloat16* __restrict__ A, const __hip_bfloat16* __restrict__ B,
    void* __restrict__ Cv, int K, int lda, int ldb, int ldc,
    long aBatch, long bBatch, long cBatch, int bzDiv, int gx, int kMode) {
    constexpr int T  = WM * WN * 64;
    constexpr int BM = WM * MI * 16;
    constexpr int BN = WN * NI * 16;
    constexpr int AE = BM * 32;
    constexpr int BE = BN * 32;
    __shared__ __hip_bfloat16 lds[4][AE + BE];

    const int tid = threadIdx.x;
    const int nwg = gridDim.x;
    const int orig = blockIdx.x;
    const int wgid = (orig & 7) * (nwg >> 3) + (orig >> 3);
    const int bx = wgid % gx, by = wgid / gx;
    const int bz = blockIdx.z;

    int kstart = 0, kend = K;
    if (kMode == 1) { if (by > bx) return; }
    else if (kMode == 2) { if (by > bx || bx - by >= 9) return; }
    else if (kMode == 3) { kend = min(K, (bx + 1) * BM); }
    else if (kMode == 4) { kend = min(K, (bx + 1) * BM); kstart = max(0, (bx - 1024 / BM) * BM); }

    const __hip_bfloat16* Ab = A + (long)bz * aBatch + (long)bx * BM * lda;
    const __hip_bfloat16* Bb = B + (long)(bz / bzDiv) * bBatch + (long)by * BN * ldb;

    const int w = tid >> 6, l = tid & 63;
    const int wm = w / WN, wn = w % WN;
    const int wrow = wm * MI * 16, wcol = wn * NI * 16;
    const int fr = l & 15, g = l >> 4;
    const int sR = tid >> 2;
    const int sc = tid & 3;

    floatx4 acc[MI][NI] = {};
    bf16x8 bfv[NI];
    bf16x8 af[MI / 2];

    auto stageA = [&](int t, int buf) {
        const int k0 = kstart + t * 32;
        #pragma unroll
        for (int i = 0; i < 2; ++i) {
            int row = sR + i * (T / 4);
            int scol = ((sc ^ ((row >> 1) & 3)) << 3);
            __builtin_amdgcn_global_load_lds(
                (kGlb*)(Ab + (long)row * lda + k0 + scol),
                (kLds*)(&lds[buf][0] + tid * 8 + i * (T * 8)), 16, 0, 0);
        }
    };
    auto stageB = [&](int t, int buf) {
        const int k0 = kstart + t * 32;
        #pragma unroll
        for (int i = 0; i < 2; ++i) {
            int row = sR + i * (T / 4);
            int scol = ((sc ^ ((row >> 1) & 3)) << 3);
            __builtin_amdgcn_global_load_lds(
                (kGlb*)(Bb + (long)row * ldb + k0 + scol),
                (kLds*)(&lds[buf][AE] + tid * 8 + i * (T * 8)), 16, 0, 0);
        }
    };

    auto phase0 = [&](int buf, int t3, bool doStage) {
        const char* AsB = (const char*)&lds[buf][0];
        const char* BsB = (const char*)&lds[buf][AE];
        #pragma unroll
        for (int mi = 0; mi < MI / 2; ++mi) {
            int ra = wrow + mi * 16 + fr;
            af[mi] = *(const bf16x8*)(AsB + ra * 64 + ((g ^ ((ra >> 1) & 3)) << 4));
        }
        #pragma unroll
        for (int ni = 0; ni < NI; ++ni) {
            int rb = wcol + ni * 16 + fr;
            bfv[ni] = *(const bf16x8*)(BsB + rb * 64 + ((g ^ ((rb >> 1) & 3)) << 4));
        }
        if (doStage) stageA(t3, t3 & 3);
        __builtin_amdgcn_s_barrier();
        asm volatile("s_waitcnt lgkmcnt(0)" ::: "memory");
        __builtin_amdgcn_sched_barrier(0);
        __builtin_amdgcn_s_setprio(1);
        #pragma unroll
        for (int mi = 0; mi < MI / 2; ++mi)
            #pragma unroll
            for (int ni = 0; ni < NI; ++ni)
                acc[mi][ni] = __builtin_amdgcn_mfma_f32_16x16x32_bf16(af[mi], bfv[ni], acc[mi][ni], 0, 0, 0);
        __builtin_amdgcn_s_setprio(0);
        __builtin_amdgcn_sched_barrier(0);
        __builtin_amdgcn_s_barrier();
    };

    auto phase1 = [&](int buf, int t3, bool doStage, int vm) {
        const char* AsB = (const char*)&lds[buf][0];
        #pragma unroll
        for (int mi = 0; mi < MI / 2; ++mi) {
            int ra = wrow + (MI / 2 + mi) * 16 + fr;
            af[mi] = *(const bf16x8*)(AsB + ra * 64 + ((g ^ ((ra >> 1) & 3)) << 4));
        }
        if (doStage) stageB(t3, t3 & 3);
        if (vm == 8)      asm volatile("s_waitcnt vmcnt(8)" ::: "memory");
        else if (vm == 4) asm volatile("s_waitcnt vmcnt(4)" ::: "memory");
        else if (vm == 0) asm volatile("s_waitcnt vmcnt(0)" ::: "memory");
        __builtin_amdgcn_s_barrier();
        asm volatile("s_waitcnt lgkmcnt(0)" ::: "memory");
        __builtin_amdgcn_sched_barrier(0);
        __builtin_amdgcn_s_setprio(1);
        #pragma unroll
        for (int mi = 0; mi < MI / 2; ++mi)
            #pragma unroll
            for (int ni = 0; ni < NI; ++ni)
                acc[MI / 2 + mi][ni] = __builtin_amdgcn_mfma_f32_16x16x32_bf16(af[mi], bfv[ni], acc[MI / 2 + mi][ni], 0, 0, 0);
        __builtin_amdgcn_s_setprio(0);
        __builtin_amdgcn_sched_barrier(0);
        __builtin_amdgcn_s_barrier();
    };

    const int nt = (kend - kstart) >> 5;
    stageA(0, 0); stageB(0, 0);
    stageA(1, 1); stageB(1, 1);
    stageA(2, 2); stageB(2, 2);
    asm volatile("s_waitcnt vmcnt(8)" ::: "memory");
    __builtin_amdgcn_s_barrier();

    for (int t = 0; t < nt - 3; ++t) {
        const int b = t & 3;
        phase0(b, t + 3, true);
        phase1(b, t + 3, true, 8);
    }
    phase0((nt - 3) & 3, 0, false); phase1((nt - 3) & 3, 0, false, 4);
    phase0((nt - 2) & 3, 0, false); phase1((nt - 2) & 3, 0, false, 0);
    phase0((nt - 1) & 3, 0, false); phase1((nt - 1) & 3, 0, false, -1);

    const long cBase = (long)bz * cBatch + (long)bx * BM * ldc + (long)by * BN;
    const int rg = (l >> 4) * 4;
    #pragma unroll
    for (int mi = 0; mi < MI; ++mi) {
        #pragma unroll
        for (int ni = 0; ni < NI; ++ni) {
            #pragma unroll
            for (int r = 0; r < 4; ++r) {
                int row = wrow + mi * 16 + rg + r;
                int col = wcol + ni * 16 + fr;
                long idx = cBase + (long)row * ldc + col;
                float v = acc[mi][ni][r];
                if constexpr (EPI == 0) {
                    ((float*)Cv)[idx] = v;
                } else {
                    ((__hip_bfloat16*)Cv)[idx] = __float2bfloat16(v);
                }
            }
        }
    }
}

// ---------------- fallback GEMM with fp32 B staging (used only if ws too small) ----------------
template<int EPI>
__global__ __launch_bounds__(256) void gemm_f32w(
    const __hip_bfloat16* __restrict__ A, const float* __restrict__ Bv,
    void* __restrict__ Cv, int K, int lda, int ldb, int ldc) {
    __shared__ __hip_bfloat16 As[128][32];
    __shared__ __hip_bfloat16 Bs[128][32];
    const int tid = threadIdx.x;
    const __hip_bfloat16* Ab = A + (long)blockIdx.x * 128 * lda;
    const float* Bb = Bv + (long)blockIdx.y * 128 * ldb;
    const int wid = tid >> 6, lane = tid & 63;
    const int wr = (wid >> 1) * 64, wc = (wid & 1) * 64;
    const int fr = lane & 15;
    const int kb = (lane >> 4) * 8;
    floatx4 acc[4][4] = {};
    for (int k0 = 0; k0 < K; k0 += 32) {
        __syncthreads();
        #pragma unroll
        for (int it = 0; it < 2; ++it) {
            int slot = tid + it * 256;
            int r = slot >> 2, c8 = (slot & 3) * 8;
            *reinterpret_cast<uint4*>(&As[r][c8]) =
                *reinterpret_cast<const uint4*>(Ab + (long)r * lda + k0 + c8);
        }
        #pragma unroll
        for (int it = 0; it < 4; ++it) {
            int slot = tid + it * 256;
            int r = slot >> 3, c4 = (slot & 7) * 4;
            float4 f = *reinterpret_cast<const float4*>(Bb + (long)r * ldb + k0 + c4);
            __hip_bfloat16 t4[4] = {__float2bfloat16(f.x), __float2bfloat16(f.y),
                                    __float2bfloat16(f.z), __float2bfloat16(f.w)};
            *reinterpret_cast<ushort4*>(&Bs[r][c4]) = *reinterpret_cast<const ushort4*>(t4);
        }
        __syncthreads();
        bf16x8 af[4], bfr[4];
        #pragma unroll
        for (int i = 0; i < 4; ++i)
            af[i] = *reinterpret_cast<const bf16x8*>(&As[wr + i * 16 + fr][kb]);
        #pragma unroll
        for (int j = 0; j < 4; ++j)
            bfr[j] = *reinterpret_cast<const bf16x8*>(&Bs[wc + j * 16 + fr][kb]);
        #pragma unroll
        for (int i = 0; i < 4; ++i)
            #pragma unroll
            for (int j = 0; j < 4; ++j)
                acc[i][j] = __builtin_amdgcn_mfma_f32_16x16x32_bf16(af[i], bfr[j], acc[i][j], 0, 0, 0);
    }
    const long cTile = (long)blockIdx.x * 128 * ldc + (long)blockIdx.y * 128;
    const int rg = (lane >> 4) * 4;
    #pragma unroll
    for (int i = 0; i < 4; ++i)
        #pragma unroll
        for (int j = 0; j < 4; ++j)
            #pragma unroll
            for (int r = 0; r < 4; ++r) {
                int row = wr + i * 16 + rg + r;
                int col = wc + j * 16 + fr;
                long idx = cTile + (long)row * ldc + col;
                float v = acc[i][j][r];
                if constexpr (EPI == 0) ((float*)Cv)[idx] = v;
                else if constexpr (EPI == 1) ((__hip_bfloat16*)Cv)[idx] = __float2bfloat16(v);
                else if constexpr (EPI == 2) {
                    float gg = 0.5f * v * (1.f + tanhf(0.7978845608f * (v + 0.044715f * v * v * v)));
                    ((__hip_bfloat16*)Cv)[idx] = __float2bfloat16(gg);
                } else ((float*)Cv)[idx] = tanhf(v * (1.f / 30.f)) * 30.f;
            }
}

// ---------------- host ----------------
extern "C" void kernel_launch(void* const* d_in, const int* in_sizes, int n_in,
                              void* d_out, int out_size, void* d_ws, size_t ws_size,
                              hipStream_t stream) {
    const int*   ids    = (const int*)d_in[0];
    const float* embedW = (const float*)d_in[1];
    const float* wq     = (const float*)d_in[2];
    const float* wk     = (const float*)d_in[3];
    const float* wv     = (const float*)d_in[4];
    const float* wo     = (const float*)d_in[5];
    const float* wg     = (const float*)d_in[6];
    const float* wu     = (const float*)d_in[7];
    const float* wd     = (const float*)d_in[8];
    const float* ln_in  = (const float*)d_in[9];
    const float* ln_pa  = (const float*)d_in[10];
    const float* ln_pf  = (const float*)d_in[11];
    const float* ln_pff = (const float*)d_in[12];
    const float* ln_f   = (const float*)d_in[13];
    const float* w_lm   = (const float*)d_in[14];
    float* out = (float*)d_out;

    char* ws = (char*)d_ws;
    size_t off = 0;
    auto alloc = [&](size_t bytes) -> void* {
        size_t o = (off + 255) & ~(size_t)255;
        off = o + bytes;
        return (void*)(ws + o);
    };

    float* h            = (float*)alloc((size_t)S * D * 4);
    __hip_bfloat16* xb  = (__hip_bfloat16*)alloc((size_t)S * D * 2);
    __hip_bfloat16* qkvb = (__hip_bfloat16*)alloc((size_t)S * 4096 * 2); // q|k|v packed
    __hip_bfloat16* vT  = (__hip_bfloat16*)alloc((size_t)NKV * HD * S * 2);
    __hip_bfloat16* ab  = (__hip_bfloat16*)alloc((size_t)S * NH * HD * 2);
    float* tmpf         = (float*)alloc((size_t)S * D * 4);
    __hip_bfloat16* guP = (__hip_bfloat16*)alloc((size_t)S * FF * 2);    // gelu(gate)*up
    __hip_bfloat16* gu  = (__hip_bfloat16*)alloc((size_t)S * 16384 * 2); // fallback only
    float* cosb         = (float*)alloc((size_t)S * 128 * 4);
    float* sinb         = (float*)alloc((size_t)S * 128 * 4);
    __hip_bfloat16* scores = (__hip_bfloat16*)alloc((size_t)NH * S * S * 2);
    __hip_bfloat16* probs  = (__hip_bfloat16*)alloc((size_t)NH * S * S * 2);

    const long SLq = 2048L * 2048, SLkv = 1024L * 2048, SLff = 8192L * 2048;
    const long nWlm = (long)VOCAB * D;
    __hip_bfloat16* wqkvb = (__hip_bfloat16*)alloc(4L * 4096 * 2048 * 2);
    __hip_bfloat16* wgub  = (__hip_bfloat16*)alloc(4L * 16384 * 2048 * 2); // interleaved wg/wu
    __hip_bfloat16* wob   = (__hip_bfloat16*)alloc(4L * SLq * 2);
    __hip_bfloat16* wdb   = (__hip_bfloat16*)alloc(4L * SLff * 2);
    __hip_bfloat16* wlmb  = (__hip_bfloat16*)alloc(nWlm * 2);
    const bool big = (off <= ws_size);
    (void)in_sizes; (void)n_in; (void)out_size;

    rope_table_kernel<<<dim3(S), dim3(128), 0, stream>>>(cosb, sinb);
    embed_kernel<<<dim3(D / 256, S), dim3(256), 0, stream>>>(ids, embedW, h);

    auto cvt = [&](const float* s, __hip_bfloat16* dp, long n) {
        long n8 = n / 8;
        long want = (n8 + 255) / 256;
        int blocks = (int)(want < 2048 ? want : 2048);
        cvt_bf16_kernel<<<dim3(blocks), dim3(256), 0, stream>>>(s, dp, n8);
    };
    auto cvtI = [&](const float* s, __hip_bfloat16* dp, int half, long n) {
        long n8 = n / 8;
        long want = (n8 + 255) / 256;
        int blocks = (int)(want < 2048 ? want : 2048);
        cvt_inter_kernel<<<dim3(blocks), dim3(256), 0, stream>>>(s, dp, half, n8);
    };
    if (big) {
        for (int l = 0; l < NLAYER; ++l) {
            cvt(wq + l * SLq,  wqkvb + (size_t)l * 4096 * 2048,                SLq);
            cvt(wk + l * SLkv, wqkvb + (size_t)l * 4096 * 2048 + 2048L * 2048, SLkv);
            cvt(wv + l * SLkv, wqkvb + (size_t)l * 4096 * 2048 + 3072L * 2048, SLkv);
            cvtI(wg + l * SLff, wgub + (size_t)l * 16384 * 2048, 0, SLff);
            cvtI(wu + l * SLff, wgub + (size_t)l * 16384 * 2048, 1, SLff);
        }
        cvt(wo, wob, 4L * SLq);
        cvt(wd, wdb, 4L * SLff);
        cvt(w_lm, wlmb, nWlm);
    }

    // launchers: p256 = 8-phase 256x256 (512 thr), p128 = 128x128 2-phase (256 thr)
    auto p256 = [&](int epi, const __hip_bfloat16* A, const __hip_bfloat16* B, void* C,
                    int K, int lda, int ldb, int ldc, int gx, int gy) {
        dim3 grid(gx * gy, 1, 1);
        if (epi == 3)
            gemm_8ph<3><<<grid, 512, 0, stream>>>(A, B, C, K, lda, ldb, ldc, gx);
        else
            gemm_8ph<5><<<grid, 512, 0, stream>>>(A, B, C, K, lda, ldb, ldc, gx);
    };
    auto p128 = [&](int epi, const __hip_bfloat16* A, const __hip_bfloat16* B, void* C,
                    int K, int lda, int ldb, int ldc, int gx, int gy, int gz,
                    long aB, long bB, long cB, int bzDiv, int kMode) {
        dim3 grid(gx * gy, 1, gz);
        switch (epi) {
        case 0: gemm_pipe<0, 2, 2, 4, 4><<<grid, 256, 0, stream>>>(A, B, C, K, lda, ldb, ldc, aB, bB, cB, bzDiv, gx, kMode); break;
        default: gemm_pipe<1, 2, 2, 4, 4><<<grid, 256, 0, stream>>>(A, B, C, K, lda, ldb, ldc, aB, bB, cB, bzDiv, gx, kMode); break;
        }
    };

    for (int l = 0; l < NLAYER; ++l) {
        int isLocal = (l % 2 == 0) ? 1 : 0;
        rms_bf16_kernel<<<dim3(S), dim3(256), 0, stream>>>(h, ln_in + l * D, xb);
        if (big) {
            p128(1, xb, wqkvb + (size_t)l * 4096 * 2048, qkvb, D, D, D, 4096, 16, 32, 1, 0, 0, 0, 1, 0);
        } else {
            gemm_f32w<1><<<dim3(16, 16), 256, 0, stream>>>(xb, wq + l * SLq, qkvb, D, D, D, 4096);
            gemm_f32w<1><<<dim3(16, 8), 256, 0, stream>>>(xb, wk + l * SLkv, qkvb + 2048, D, D, D, 4096);
            gemm_f32w<1><<<dim3(16, 8), 256, 0, stream>>>(xb, wv + l * SLkv, qkvb + 3072, D, D, D, 4096);
        }
        rope_kernel<<<dim3(S, NH), dim3(128), 0, stream>>>(qkvb, cosb, sinb, 4096);
        rope_kernel<<<dim3(S, NKV), dim3(128), 0, stream>>>(qkvb + 2048, cosb, sinb, 4096);
        transpose_v_kernel<<<dim3(S / 64, HD / 64, NKV), 256, 0, stream>>>(qkvb + 3072, vT, 4096);
        // scores = q @ k^T per head (bf16 out), masked-tile skip
        p128(1, qkvb, qkvb + 2048, scores, HD, 4096, 4096, S, 16, 16, NH,
             (long)HD, (long)HD, (long)S * S, 2, isLocal ? 2 : 1);
        softmax_kernel<<<dim3(S, NH), dim3(256), 0, stream>>>(scores, probs, isLocal);
        // a = probs @ vT, K-range restricted to valid band
        p128(1, probs, vT, ab, S, S, S, NH * HD, 16, 2, NH,
             (long)S * S, (long)HD * S, (long)HD, 2, isLocal ? 4 : 3);
        if (big) {
            p128(0, ab, wob + (size_t)l * SLq, tmpf, NH * HD, NH * HD, NH * HD, D, 16, 16, 1, 0, 0, 0, 1, 0);
        } else {
            gemm_f32w<0><<<dim3(16, 16), 256, 0, stream>>>(ab, wo + l * SLq, tmpf, NH * HD, NH * HD, NH * HD, D);
        }
        resid_rms_kernel<<<dim3(S), dim3(256), 0, stream>>>(h, tmpf, ln_pa + l * D);
        rms_bf16_kernel<<<dim3(S), dim3(256), 0, stream>>>(h, ln_pf + l * D, xb);
        if (big) {
            // fused gate|up with interleaved rows; epilogue writes gelu(gate)*up -> guP [S][8192]
            p256(5, xb, wgub + (size_t)l * 16384 * 2048, guP, D, D, D, FF, 8, 64);
        } else {
            gemm_f32w<2><<<dim3(16, 64), 256, 0, stream>>>(xb, wg + l * SLff, gu, D, D, D, 16384);
            gemm_f32w<1><<<dim3(16, 64), 256, 0, stream>>>(xb, wu + l * SLff, gu + 8192, D, D, D, 16384);
            mul_gu_kernel<<<dim3((S * FF) / (256 * 8)), 256, 0, stream>>>(gu);
        }
        if (big) {
            p128(0, guP, wdb + (size_t)l * SLff, tmpf, FF, FF, FF, D, 16, 16, 1, 0, 0, 0, 1, 0);
        } else {
            gemm_f32w<0><<<dim3(16, 16), 256, 0, stream>>>(gu, wd + l * SLff, tmpf, FF, 16384, FF, D);
        }
        resid_rms_kernel<<<dim3(S), dim3(256), 0, stream>>>(h, tmpf, ln_pff + l * D);
    }

    rms_bf16_kernel<<<dim3(S), dim3(256), 0, stream>>>(h, ln_f, xb);
    if (big) {
        p256(3, xb, wlmb, out, D, D, D, VOCAB, 8, VOCAB / 256);
    } else {
        gemm_f32w<3><<<dim3(16, VOCAB / 128), 256, 0, stream>>>(xb, w_lm, out, D, D, D, VOCAB);
    }
}

// Round 9
// 2555.694 us; speedup vs baseline: 1.0816x; 1.0066x over previous
//
#include <hip/hip_runtime.h>
#include <hip/hip_bf16.h>

typedef __attribute__((ext_vector_type(8))) __bf16 bf16x8;
typedef __attribute__((ext_vector_type(4))) float floatx4;

typedef __attribute__((address_space(1))) const unsigned char kGlb;
typedef __attribute__((address_space(3))) unsigned char kLds;

static constexpr int S = 2048;
static constexpr int D = 2048;
static constexpr int HD = 256;
static constexpr int NH = 8;
static constexpr int NKV = 4;
static constexpr int NLAYER = 4;
static constexpr int VOCAB = 32000;
static constexpr int FF = 8192;
static constexpr int WINDOW = 1024;

// ---------------- block reduction helpers (256 threads = 4 waves) ----------------
__device__ __forceinline__ float blk_sum(float v) {
    __shared__ float sm[4];
    #pragma unroll
    for (int o = 32; o > 0; o >>= 1) v += __shfl_down(v, o, 64);
    int lane = threadIdx.x & 63, w = threadIdx.x >> 6;
    __syncthreads();
    if (lane == 0) sm[w] = v;
    __syncthreads();
    return sm[0] + sm[1] + sm[2] + sm[3];
}

__device__ __forceinline__ float blk_max(float v) {
    __shared__ float sm[4];
    #pragma unroll
    for (int o = 32; o > 0; o >>= 1) v = fmaxf(v, __shfl_down(v, o, 64));
    int lane = threadIdx.x & 63, w = threadIdx.x >> 6;
    __syncthreads();
    if (lane == 0) sm[w] = v;
    __syncthreads();
    return fmaxf(fmaxf(sm[0], sm[1]), fmaxf(sm[2], sm[3]));
}

// ---------------- elementwise kernels ----------------
__global__ void embed_kernel(const int* __restrict__ ids, const float* __restrict__ E,
                             float* __restrict__ h) {
    int d = blockIdx.x * 256 + threadIdx.x;
    int s = blockIdx.y;
    h[(long)s * D + d] = E[(long)ids[s] * D + d] * 45.25483399593904f; // sqrt(2048)
}

__global__ void rope_table_kernel(float* __restrict__ c, float* __restrict__ sn) {
    int i = threadIdx.x;   // 0..127
    int p = blockIdx.x;    // 0..S-1
    float inv = powf(10000.f, -(float)i / 128.f);
    float a = (float)p * inv;
    c[p * 128 + i] = cosf(a);
    sn[p * 128 + i] = sinf(a);
}

// fp32 -> bf16 conversion (grid-stride, 8 elems/thread/iter)
__global__ void cvt_bf16_kernel(const float* __restrict__ src, __hip_bfloat16* __restrict__ dst,
                                long n8) {
    long stride = (long)gridDim.x * 256;
    for (long i = (long)blockIdx.x * 256 + threadIdx.x; i < n8; i += stride) {
        long o = i * 8;
        float4 a = *(const float4*)(src + o);
        float4 b = *(const float4*)(src + o + 4);
        __hip_bfloat16 h8[8] = {
            __float2bfloat16(a.x), __float2bfloat16(a.y),
            __float2bfloat16(a.z), __float2bfloat16(a.w),
            __float2bfloat16(b.x), __float2bfloat16(b.y),
            __float2bfloat16(b.z), __float2bfloat16(b.w)};
        *(uint4*)(dst + o) = *(const uint4*)h8;
    }
}

// fp32 (rows x 2048) -> bf16 at interleaved rows: dst row = 2*row + half
__global__ void cvt_inter_kernel(const float* __restrict__ src, __hip_bfloat16* __restrict__ dst,
                                 int half, long n8) {
    long stride = (long)gridDim.x * 256;
    for (long i = (long)blockIdx.x * 256 + threadIdx.x; i < n8; i += stride) {
        long o = i * 8;
        long row = o >> 11, col = o & 2047;
        float4 a = *(const float4*)(src + o);
        float4 b = *(const float4*)(src + o + 4);
        __hip_bfloat16 h8[8] = {
            __float2bfloat16(a.x), __float2bfloat16(a.y),
            __float2bfloat16(a.z), __float2bfloat16(a.w),
            __float2bfloat16(b.x), __float2bfloat16(b.y),
            __float2bfloat16(b.z), __float2bfloat16(b.w)};
        *(uint4*)(dst + ((row * 2 + half) << 11) + col) = *(const uint4*)h8;
    }
}

// x = rms(h, w) -> bf16
__global__ void rms_bf16_kernel(const float* __restrict__ h, const float* __restrict__ w,
                                __hip_bfloat16* __restrict__ o) {
    int s = blockIdx.x;
    const float* row = h + (long)s * D;
    float vals[8], ss = 0.f;
    #pragma unroll
    for (int t = 0; t < 8; ++t) {
        int j = t * 256 + threadIdx.x;
        float v = row[j]; vals[t] = v; ss += v * v;
    }
    ss = blk_sum(ss);
    float r = rsqrtf(ss * (1.f / D) + 1e-6f);
    #pragma unroll
    for (int t = 0; t < 8; ++t) {
        int j = t * 256 + threadIdx.x;
        o[(long)s * D + j] = __float2bfloat16(vals[t] * r * (1.f + w[j]));
    }
}

// h += rms(t, w)
__global__ void resid_rms_kernel(float* __restrict__ h, const float* __restrict__ tt,
                                 const float* __restrict__ w) {
    int s = blockIdx.x;
    const float* row = tt + (long)s * D;
    float* hr = h + (long)s * D;
    float vals[8], ss = 0.f;
    #pragma unroll
    for (int t = 0; t < 8; ++t) {
        int j = t * 256 + threadIdx.x;
        float v = row[j]; vals[t] = v; ss += v * v;
    }
    ss = blk_sum(ss);
    float r = rsqrtf(ss * (1.f / D) + 1e-6f);
    #pragma unroll
    for (int t = 0; t < 8; ++t) {
        int j = t * 256 + threadIdx.x;
        hr[j] += vals[t] * r * (1.f + w[j]);
    }
}

// in-place RoPE on rows with stride ldx; head offset hh*HD; 128 threads per (s, head)
__global__ void rope_kernel(__hip_bfloat16* __restrict__ x, const float* __restrict__ cb,
                            const float* __restrict__ sb, int ldx) {
    int s = blockIdx.x, hh = blockIdx.y, i = threadIdx.x; // i in 0..127
    __hip_bfloat16* p = x + (long)s * ldx + hh * HD;
    float x1 = __bfloat162float(p[i]);
    float x2 = __bfloat162float(p[128 + i]);
    float c = cb[s * 128 + i], sn = sb[s * 128 + i];
    p[i]       = __float2bfloat16(x1 * c - x2 * sn);
    p[128 + i] = __float2bfloat16(x1 * sn + x2 * c);
}

// v rows (stride ldv) -> vT (NKV, HD, S) bf16
__global__ void transpose_v_kernel(const __hip_bfloat16* __restrict__ v,
                                   __hip_bfloat16* __restrict__ vt, int ldv) {
    __shared__ ushort tile[64][65];
    int s0 = blockIdx.x * 64, d0 = blockIdx.y * 64, kv = blockIdx.z;
    const ushort* vin = (const ushort*)v;
    ushort* vout = (ushort*)vt;
    #pragma unroll
    for (int it = 0; it < 4; ++it) {
        int slot = it * 256 + threadIdx.x;
        int r = slot >> 4, c4 = (slot & 15) << 2;
        ushort4 x = *(const ushort4*)(vin + (long)(s0 + r) * ldv + kv * HD + d0 + c4);
        tile[r][c4] = x.x; tile[r][c4 + 1] = x.y; tile[r][c4 + 2] = x.z; tile[r][c4 + 3] = x.w;
    }
    __syncthreads();
    #pragma unroll
    for (int it = 0; it < 4; ++it) {
        int slot = it * 256 + threadIdx.x;
        int rr = slot >> 4, c4 = (slot & 15) << 2;
        ushort4 y;
        y.x = tile[c4][rr]; y.y = tile[c4 + 1][rr]; y.z = tile[c4 + 2][rr]; y.w = tile[c4 + 3][rr];
        *(ushort4*)(vout + (long)kv * HD * S + (long)(d0 + rr) * S + s0 + c4) = y;
    }
}

// scores (NH,S,S) bf16 -> probs bf16, with scale, tanh softcap, mask, softmax.
__global__ void softmax_kernel(const __hip_bfloat16* __restrict__ sc,
                               __hip_bfloat16* __restrict__ pr, int isLocal) {
    int i = blockIdx.x, hh = blockIdx.y;
    const __hip_bfloat16* row = sc + ((long)hh * S + i) * S;
    __hip_bfloat16* orow = pr + ((long)hh * S + i) * S;
    int lo = isLocal ? max(0, i - (WINDOW - 1)) : 0;
    float vals[8];
    float m = -3.0e38f;
    #pragma unroll
    for (int t = 0; t < 8; ++t) {
        int j = t * 256 + threadIdx.x;
        bool chunkAny = (t * 256 <= i) && (t * 256 + 255 >= lo);
        if (chunkAny) {
            bool valid = (j <= i) && (j >= lo);
            float v = tanhf(__bfloat162float(row[j]) * (0.0625f / 50.f)) * 50.f;
            vals[t] = valid ? v : -3.0e38f;
            m = fmaxf(m, vals[t]);
        } else {
            vals[t] = -3.0e38f;
        }
    }
    m = blk_max(m);
    float ps[8], ssum = 0.f;
    #pragma unroll
    for (int t = 0; t < 8; ++t) {
        float p = (vals[t] > -1.0e38f) ? __expf(vals[t] - m) : 0.f;
        ps[t] = p; ssum += p;
    }
    ssum = blk_sum(ssum);
    float inv = 1.f / ssum;
    #pragma unroll
    for (int t = 0; t < 8; ++t) {
        int j = t * 256 + threadIdx.x;
        orow[j] = __float2bfloat16(ps[t] * inv);
    }
}

// gate half *= up half, packed gu[S][16384] (fallback path only)
__global__ void mul_gu_kernel(__hip_bfloat16* __restrict__ gu) {
    long idx = ((long)blockIdx.x * 256 + threadIdx.x) * 8;
    long s = idx >> 13;
    long f = idx & 8191;
    __hip_bfloat16* gp = gu + s * 16384 + f;
    const __hip_bfloat16* up = gu + s * 16384 + 8192 + f;
    uint4 gv = *(const uint4*)gp;
    uint4 uv = *(const uint4*)up;
    const __hip_bfloat16* gb = (const __hip_bfloat16*)&gv;
    const __hip_bfloat16* ub = (const __hip_bfloat16*)&uv;
    __hip_bfloat16 o[8];
    #pragma unroll
    for (int j = 0; j < 8; ++j)
        o[j] = __float2bfloat16(__bfloat162float(gb[j]) * __bfloat162float(ub[j]));
    *(uint4*)gp = *(const uint4*)o;
}

// ================= 8-phase 256x256 GEMM with cross-phase read-ahead =================
// BK=64, 8 waves (2Mx4N); even K-tiles -> buf0, odd -> buf1; halves = 128 rows (128 KiB LDS).
// Key (m201 overlap): ds_reads for phase p+1 issue BEFORE phase p's MFMA, gated by a COUNTED
// lgkmcnt(n) that waits only for phase p's fragments -> LDS-read time hides under MFMA.
// One barrier/phase. Stages (tile t+1): ph0=A0, ph1=B0, ph2=B1, ph3=A1; vmcnt(4) each phase
// confirms exactly the half the next RD needs (invariant: 4 loads outstanding entering a tile).
// Register sets alternate: af(half0) / af2(half1) / bf0 / bf1 -- no extra buffering.
// Swizzle: 16B chunk c ^= (row&7) within 128B rows, on BOTH gload source and ds_read.
// EPI: 3 = tanh(x/30)*30 -> f32 (LM head); 5 = interleaved gelu(gate)*up -> bf16.  nt >= 2.
#define RD_AF(DST, BUF, HALF)                                                     \
    {                                                                             \
        const char* _p = (const char*)&ldsA[BUF][HALF][0];                        \
        _Pragma("unroll")                                                         \
        for (int mi = 0; mi < 4; ++mi) {                                          \
            int r = wm * 64 + mi * 16 + fr;                                       \
            _Pragma("unroll")                                                     \
            for (int ks = 0; ks < 2; ++ks) {                                      \
                int c = ks * 4 + g;                                               \
                DST[mi][ks] = *(const bf16x8*)(_p + r * 128 + ((c ^ (r & 7)) << 4)); \
            }                                                                     \
        }                                                                         \
    }

#define RD_BF(DST, BUF, HALF)                                                     \
    {                                                                             \
        const char* _p = (const char*)&ldsB[BUF][HALF][0];                        \
        _Pragma("unroll")                                                         \
        for (int ni = 0; ni < 2; ++ni) {                                          \
            int r = wn * 32 + ni * 16 + fr;                                       \
            _Pragma("unroll")                                                     \
            for (int ks = 0; ks < 2; ++ks) {                                      \
                int c = ks * 4 + g;                                               \
                DST[ni][ks] = *(const bf16x8*)(_p + r * 128 + ((c ^ (r & 7)) << 4)); \
            }                                                                     \
        }                                                                         \
    }

#define MM(QM, QN, AF, BF)                                                        \
    __builtin_amdgcn_s_setprio(1);                                                \
    _Pragma("unroll")                                                             \
    for (int mi = 0; mi < 4; ++mi)                                                \
        _Pragma("unroll")                                                         \
        for (int ni = 0; ni < 2; ++ni)                                            \
            _Pragma("unroll")                                                     \
            for (int ks = 0; ks < 2; ++ks)                                        \
                acc[QM][QN][mi][ni] = __builtin_amdgcn_mfma_f32_16x16x32_bf16(    \
                    AF[mi][ks], BF[ni][ks], acc[QM][QN][mi][ni], 0, 0, 0);        \
    __builtin_amdgcn_s_setprio(0);

template<int EPI>
__global__ __launch_bounds__(512, 2) void gemm_8ph(
    const __hip_bfloat16* __restrict__ A, const __hip_bfloat16* __restrict__ B,
    void* __restrict__ Cv, int K, int lda, int ldb, int ldc, int gx) {
    __shared__ __hip_bfloat16 ldsA[2][2][8192];   // [buf][half][128*64]
    __shared__ __hip_bfloat16 ldsB[2][2][8192];
    const int tid = threadIdx.x;
    const int nwg = gridDim.x;
    const int orig = blockIdx.x;
    const int wgid = (orig & 7) * (nwg >> 3) + (orig >> 3);   // nwg % 8 == 0
    const int bx = wgid % gx, by = wgid / gx;

    const __hip_bfloat16* Ab = A + (long)bx * 256 * lda;
    const __hip_bfloat16* Bb = B + (long)by * 256 * ldb;

    const int w = tid >> 6, l = tid & 63;
    const int wm = w >> 2, wn = w & 3;   // 2 x 4 wave grid
    const int fr = l & 15, g = l >> 4;
    const int sRow0 = tid >> 3;
    const int sCh = tid & 7;

    floatx4 acc[2][2][4][2] = {};
    bf16x8 af[4][2], af2[4][2], bf0[2][2], bf1[2][2];

    auto stage = [&](const __hip_bfloat16* src, int ld, int k0, __hip_bfloat16* dst) {
        #pragma unroll
        for (int i = 0; i < 2; ++i) {
            int row = sRow0 + i * 64;
            int cs = (sCh ^ (row & 7)) * 8;
            __builtin_amdgcn_global_load_lds(
                (kGlb*)(src + (long)row * ld + k0 + cs),
                (kLds*)((char*)dst + i * 8192 + tid * 16), 16, 0, 0);
        }
    };

    const int nt = K >> 6;   // requires nt >= 2
    // prologue: tile0 halves A0,B0,B1,A1 (8 loads); confirm A0,B0; RD(0)
    stage(Ab,             lda, 0, &ldsA[0][0][0]);
    stage(Bb,             ldb, 0, &ldsB[0][0][0]);
    stage(Bb + 128 * ldb, ldb, 0, &ldsB[0][1][0]);
    stage(Ab + 128 * lda, lda, 0, &ldsA[0][1][0]);
    asm volatile("s_waitcnt vmcnt(4)" ::: "memory");
    __builtin_amdgcn_s_barrier();
    RD_AF(af, 0, 0);
    RD_BF(bf0, 0, 0);

    for (int t = 0; t < nt; ++t) {
        const int b = t & 1, nb = b ^ 1;
        const int kn = (t + 1) * 64;
        const bool last = (t == nt - 1);
        // ---- ph0: MM(0,0) af,bf0 ; stage A0(t+1) ; RD bf1 ----
        if (!last) {
            stage(Ab, lda, kn, &ldsA[nb][0][0]);
            asm volatile("s_waitcnt vmcnt(4)" ::: "memory");
        } else {
            asm volatile("s_waitcnt vmcnt(2)" ::: "memory");
        }
        __builtin_amdgcn_s_barrier();
        RD_BF(bf1, b, 1);
        asm volatile("s_waitcnt lgkmcnt(4)" ::: "memory");
        __builtin_amdgcn_sched_barrier(0);
        MM(0, 0, af, bf0)
        __builtin_amdgcn_sched_barrier(0);
        // ---- ph1: MM(0,1) af,bf1 ; stage B0(t+1) ; RD af2 ----
        if (!last) {
            stage(Bb, ldb, kn, &ldsB[nb][0][0]);
            asm volatile("s_waitcnt vmcnt(4)" ::: "memory");
        } else {
            asm volatile("s_waitcnt vmcnt(0)" ::: "memory");
        }
        __builtin_amdgcn_s_barrier();
        RD_AF(af2, b, 1);
        asm volatile("s_waitcnt lgkmcnt(8)" ::: "memory");
        __builtin_amdgcn_sched_barrier(0);
        MM(0, 1, af, bf1)
        __builtin_amdgcn_sched_barrier(0);
        // ---- ph2: MM(1,0) af2,bf0 ; stage B1(t+1) ----
        if (!last) {
            stage(Bb + 128 * ldb, ldb, kn, &ldsB[nb][1][0]);
            asm volatile("s_waitcnt vmcnt(4)" ::: "memory");
        }
        __builtin_amdgcn_s_barrier();
        asm volatile("s_waitcnt lgkmcnt(0)" ::: "memory");
        __builtin_amdgcn_sched_barrier(0);
        MM(1, 0, af2, bf0)
        __builtin_amdgcn_sched_barrier(0);
        // ---- ph3: MM(1,1) af2,bf1 ; stage A1(t+1) ; RD next af,bf0 ----
        if (!last) {
            stage(Ab + 128 * lda, lda, kn, &ldsA[nb][1][0]);
            asm volatile("s_waitcnt vmcnt(4)" ::: "memory");
        }
        __builtin_amdgcn_s_barrier();
        if (!last) {
            RD_AF(af, nb, 0);
            RD_BF(bf0, nb, 0);
        }
        __builtin_amdgcn_sched_barrier(0);
        MM(1, 1, af2, bf1)
        __builtin_amdgcn_sched_barrier(0);
    }

    const long cBase = (long)bx * 256 * ldc + (long)by * 256;
    const int rg = (l >> 4) * 4;
    #pragma unroll
    for (int qm = 0; qm < 2; ++qm)
    #pragma unroll
    for (int qn = 0; qn < 2; ++qn)
    #pragma unroll
    for (int mi = 0; mi < 4; ++mi)
    #pragma unroll
    for (int ni = 0; ni < 2; ++ni)
    #pragma unroll
    for (int r = 0; r < 4; ++r) {
        int row = qm * 128 + wm * 64 + mi * 16 + rg + r;
        int col = qn * 128 + wn * 32 + ni * 16 + fr;
        float v = acc[qm][qn][mi][ni][r];
        if constexpr (EPI == 3) {
            ((float*)Cv)[cBase + (long)row * ldc + col] = tanhf(v * (1.f / 30.f)) * 30.f;
        } else { // EPI 5: B rows interleaved wg/wu; even col = gate, odd = up
            float pv = __shfl_xor(v, 1);
            if (!(fr & 1)) {
                float gg = 0.5f * v * (1.f + tanhf(0.7978845608f * (v + 0.044715f * v * v * v)));
                long idx5 = ((long)bx * 256 + row) * (long)ldc + (long)by * 128 + (col >> 1);
                ((__hip_bfloat16*)Cv)[idx5] = __float2bfloat16(gg * pv);
            }
        }
    }
}

// ---------------- generic pipelined GEMM (128x128 path, unchanged) ----------------
template<int EPI, int WM, int WN, int MI, int NI>
__global__ __launch_bounds__(WM*WN*64, 2) void gemm_pipe(
    const __hip_bfloat16* __restrict__ A, const __hip_bfloat16* __restrict__ B,
    void* __restrict__ Cv, int K, int lda, int ldb, int ldc,
    long aBatch, long bBatch, long cBatch, int bzDiv, int gx, int kMode) {
    constexpr int T  = WM * WN * 64;
    constexpr int BM = WM * MI * 16;
    constexpr int BN = WN * NI * 16;
    constexpr int AE = BM * 32;
    constexpr int BE = BN * 32;
    __shared__ __hip_bfloat16 lds[4][AE + BE];

    const int tid = threadIdx.x;
    const int nwg = gridDim.x;
    const int orig = blockIdx.x;
    const int wgid = (orig & 7) * (nwg >> 3) + (orig >> 3);
    const int bx = wgid % gx, by = wgid / gx;
    const int bz = blockIdx.z;

    int kstart = 0, kend = K;
    if (kMode == 1) { if (by > bx) return; }
    else if (kMode == 2) { if (by > bx || bx - by >= 9) return; }
    else if (kMode == 3) { kend = min(K, (bx + 1) * BM); }
    else if (kMode == 4) { kend = min(K, (bx + 1) * BM); kstart = max(0, (bx - 1024 / BM) * BM); }

    const __hip_bfloat16* Ab = A + (long)bz * aBatch + (long)bx * BM * lda;
    const __hip_bfloat16* Bb = B + (long)(bz / bzDiv) * bBatch + (long)by * BN * ldb;

    const int w = tid >> 6, l = tid & 63;
    const int wm = w / WN, wn = w % WN;
    const int wrow = wm * MI * 16, wcol = wn * NI * 16;
    const int fr = l & 15, g = l >> 4;
    const int sR = tid >> 2;
    const int sc = tid & 3;

    floatx4 acc[MI][NI] = {};
    bf16x8 bfv[NI];
    bf16x8 af[MI / 2];

    auto stageA = [&](int t, int buf) {
        const int k0 = kstart + t * 32;
        #pragma unroll
        for (int i = 0; i < 2; ++i) {
            int row = sR + i * (T / 4);
            int scol = ((sc ^ ((row >> 1) & 3)) << 3);
            __builtin_amdgcn_global_load_lds(
                (kGlb*)(Ab + (long)row * lda + k0 + scol),
                (kLds*)(&lds[buf][0] + tid * 8 + i * (T * 8)), 16, 0, 0);
        }
    };
    auto stageB = [&](int t, int buf) {
        const int k0 = kstart + t * 32;
        #pragma unroll
        for (int i = 0; i < 2; ++i) {
            int row = sR + i * (T / 4);
            int scol = ((sc ^ ((row >> 1) & 3)) << 3);
            __builtin_amdgcn_global_load_lds(
                (kGlb*)(Bb + (long)row * ldb + k0 + scol),
                (kLds*)(&lds[buf][AE] + tid * 8 + i * (T * 8)), 16, 0, 0);
        }
    };

    auto phase0 = [&](int buf, int t3, bool doStage) {
        const char* AsB = (const char*)&lds[buf][0];
        const char* BsB = (const char*)&lds[buf][AE];
        #pragma unroll
        for (int mi = 0; mi < MI / 2; ++mi) {
            int ra = wrow + mi * 16 + fr;
            af[mi] = *(const bf16x8*)(AsB + ra * 64 + ((g ^ ((ra >> 1) & 3)) << 4));
        }
        #pragma unroll
        for (int ni = 0; ni < NI; ++ni) {
            int rb = wcol + ni * 16 + fr;
            bfv[ni] = *(const bf16x8*)(BsB + rb * 64 + ((g ^ ((rb >> 1) & 3)) << 4));
        }
        if (doStage) stageA(t3, t3 & 3);
        __builtin_amdgcn_s_barrier();
        asm volatile("s_waitcnt lgkmcnt(0)" ::: "memory");
        __builtin_amdgcn_sched_barrier(0);
        __builtin_amdgcn_s_setprio(1);
        #pragma unroll
        for (int mi = 0; mi < MI / 2; ++mi)
            #pragma unroll
            for (int ni = 0; ni < NI; ++ni)
                acc[mi][ni] = __builtin_amdgcn_mfma_f32_16x16x32_bf16(af[mi], bfv[ni], acc[mi][ni], 0, 0, 0);
        __builtin_amdgcn_s_setprio(0);
        __builtin_amdgcn_sched_barrier(0);
        __builtin_amdgcn_s_barrier();
    };

    auto phase1 = [&](int buf, int t3, bool doStage, int vm) {
        const char* AsB = (const char*)&lds[buf][0];
        #pragma unroll
        for (int mi = 0; mi < MI / 2; ++mi) {
            int ra = wrow + (MI / 2 + mi) * 16 + fr;
            af[mi] = *(const bf16x8*)(AsB + ra * 64 + ((g ^ ((ra >> 1) & 3)) << 4));
        }
        if (doStage) stageB(t3, t3 & 3);
        if (vm == 8)      asm volatile("s_waitcnt vmcnt(8)" ::: "memory");
        else if (vm == 4) asm volatile("s_waitcnt vmcnt(4)" ::: "memory");
        else if (vm == 0) asm volatile("s_waitcnt vmcnt(0)" ::: "memory");
        __builtin_amdgcn_s_barrier();
        asm volatile("s_waitcnt lgkmcnt(0)" ::: "memory");
        __builtin_amdgcn_sched_barrier(0);
        __builtin_amdgcn_s_setprio(1);
        #pragma unroll
        for (int mi = 0; mi < MI / 2; ++mi)
            #pragma unroll
            for (int ni = 0; ni < NI; ++ni)
                acc[MI / 2 + mi][ni] = __builtin_amdgcn_mfma_f32_16x16x32_bf16(af[mi], bfv[ni], acc[MI / 2 + mi][ni], 0, 0, 0);
        __builtin_amdgcn_s_setprio(0);
        __builtin_amdgcn_sched_barrier(0);
        __builtin_amdgcn_s_barrier();
    };

    const int nt = (kend - kstart) >> 5;
    stageA(0, 0); stageB(0, 0);
    stageA(1, 1); stageB(1, 1);
    stageA(2, 2); stageB(2, 2);
    asm volatile("s_waitcnt vmcnt(8)" ::: "memory");
    __builtin_amdgcn_s_barrier();

    for (int t = 0; t < nt - 3; ++t) {
        const int b = t & 3;
        phase0(b, t + 3, true);
        phase1(b, t + 3, true, 8);
    }
    phase0((nt - 3) & 3, 0, false); phase1((nt - 3) & 3, 0, false, 4);
    phase0((nt - 2) & 3, 0, false); phase1((nt - 2) & 3, 0, false, 0);
    phase0((nt - 1) & 3, 0, false); phase1((nt - 1) & 3, 0, false, -1);

    const long cBase = (long)bz * cBatch + (long)bx * BM * ldc + (long)by * BN;
    const int rg = (l >> 4) * 4;
    #pragma unroll
    for (int mi = 0; mi < MI; ++mi) {
        #pragma unroll
        for (int ni = 0; ni < NI; ++ni) {
            #pragma unroll
            for (int r = 0; r < 4; ++r) {
                int row = wrow + mi * 16 + rg + r;
                int col = wcol + ni * 16 + fr;
                long idx = cBase + (long)row * ldc + col;
                float v = acc[mi][ni][r];
                if constexpr (EPI == 0) {
                    ((float*)Cv)[idx] = v;
                } else {
                    ((__hip_bfloat16*)Cv)[idx] = __float2bfloat16(v);
                }
            }
        }
    }
}

// ---------------- fallback GEMM with fp32 B staging (used only if ws too small) ----------------
template<int EPI>
__global__ __launch_bounds__(256) void gemm_f32w(
    const __hip_bfloat16* __restrict__ A, const float* __restrict__ Bv,
    void* __restrict__ Cv, int K, int lda, int ldb, int ldc) {
    __shared__ __hip_bfloat16 As[128][32];
    __shared__ __hip_bfloat16 Bs[128][32];
    const int tid = threadIdx.x;
    const __hip_bfloat16* Ab = A + (long)blockIdx.x * 128 * lda;
    const float* Bb = Bv + (long)blockIdx.y * 128 * ldb;
    const int wid = tid >> 6, lane = tid & 63;
    const int wr = (wid >> 1) * 64, wc = (wid & 1) * 64;
    const int fr = lane & 15;
    const int kb = (lane >> 4) * 8;
    floatx4 acc[4][4] = {};
    for (int k0 = 0; k0 < K; k0 += 32) {
        __syncthreads();
        #pragma unroll
        for (int it = 0; it < 2; ++it) {
            int slot = tid + it * 256;
            int r = slot >> 2, c8 = (slot & 3) * 8;
            *reinterpret_cast<uint4*>(&As[r][c8]) =
                *reinterpret_cast<const uint4*>(Ab + (long)r * lda + k0 + c8);
        }
        #pragma unroll
        for (int it = 0; it < 4; ++it) {
            int slot = tid + it * 256;
            int r = slot >> 3, c4 = (slot & 7) * 4;
            float4 f = *reinterpret_cast<const float4*>(Bb + (long)r * ldb + k0 + c4);
            __hip_bfloat16 t4[4] = {__float2bfloat16(f.x), __float2bfloat16(f.y),
                                    __float2bfloat16(f.z), __float2bfloat16(f.w)};
            *reinterpret_cast<ushort4*>(&Bs[r][c4]) = *reinterpret_cast<const ushort4*>(t4);
        }
        __syncthreads();
        bf16x8 af[4], bfr[4];
        #pragma unroll
        for (int i = 0; i < 4; ++i)
            af[i] = *reinterpret_cast<const bf16x8*>(&As[wr + i * 16 + fr][kb]);
        #pragma unroll
        for (int j = 0; j < 4; ++j)
            bfr[j] = *reinterpret_cast<const bf16x8*>(&Bs[wc + j * 16 + fr][kb]);
        #pragma unroll
        for (int i = 0; i < 4; ++i)
            #pragma unroll
            for (int j = 0; j < 4; ++j)
                acc[i][j] = __builtin_amdgcn_mfma_f32_16x16x32_bf16(af[i], bfr[j], acc[i][j], 0, 0, 0);
    }
    const long cTile = (long)blockIdx.x * 128 * ldc + (long)blockIdx.y * 128;
    const int rg = (lane >> 4) * 4;
    #pragma unroll
    for (int i = 0; i < 4; ++i)
        #pragma unroll
        for (int j = 0; j < 4; ++j)
            #pragma unroll
            for (int r = 0; r < 4; ++r) {
                int row = wr + i * 16 + rg + r;
                int col = wc + j * 16 + fr;
                long idx = cTile + (long)row * ldc + col;
                float v = acc[i][j][r];
                if constexpr (EPI == 0) ((float*)Cv)[idx] = v;
                else if constexpr (EPI == 1) ((__hip_bfloat16*)Cv)[idx] = __float2bfloat16(v);
                else if constexpr (EPI == 2) {
                    float gg = 0.5f * v * (1.f + tanhf(0.7978845608f * (v + 0.044715f * v * v * v)));
                    ((__hip_bfloat16*)Cv)[idx] = __float2bfloat16(gg);
                } else ((float*)Cv)[idx] = tanhf(v * (1.f / 30.f)) * 30.f;
            }
}

// ---------------- host ----------------
extern "C" void kernel_launch(void* const* d_in, const int* in_sizes, int n_in,
                              void* d_out, int out_size, void* d_ws, size_t ws_size,
                              hipStream_t stream) {
    const int*   ids    = (const int*)d_in[0];
    const float* embedW = (const float*)d_in[1];
    const float* wq     = (const float*)d_in[2];
    const float* wk     = (const float*)d_in[3];
    const float* wv     = (const float*)d_in[4];
    const float* wo     = (const float*)d_in[5];
    const float* wg     = (const float*)d_in[6];
    const float* wu     = (const float*)d_in[7];
    const float* wd     = (const float*)d_in[8];
    const float* ln_in  = (const float*)d_in[9];
    const float* ln_pa  = (const float*)d_in[10];
    const float* ln_pf  = (const float*)d_in[11];
    const float* ln_pff = (const float*)d_in[12];
    const float* ln_f   = (const float*)d_in[13];
    const float* w_lm   = (const float*)d_in[14];
    float* out = (float*)d_out;

    char* ws = (char*)d_ws;
    size_t off = 0;
    auto alloc = [&](size_t bytes) -> void* {
        size_t o = (off + 255) & ~(size_t)255;
        off = o + bytes;
        return (void*)(ws + o);
    };

    float* h            = (float*)alloc((size_t)S * D * 4);
    __hip_bfloat16* xb  = (__hip_bfloat16*)alloc((size_t)S * D * 2);
    __hip_bfloat16* qkvb = (__hip_bfloat16*)alloc((size_t)S * 4096 * 2); // q|k|v packed
    __hip_bfloat16* vT  = (__hip_bfloat16*)alloc((size_t)NKV * HD * S * 2);
    __hip_bfloat16* ab  = (__hip_bfloat16*)alloc((size_t)S * NH * HD * 2);
    float* tmpf         = (float*)alloc((size_t)S * D * 4);
    __hip_bfloat16* guP = (__hip_bfloat16*)alloc((size_t)S * FF * 2);    // gelu(gate)*up
    __hip_bfloat16* gu  = (__hip_bfloat16*)alloc((size_t)S * 16384 * 2); // fallback only
    float* cosb         = (float*)alloc((size_t)S * 128 * 4);
    float* sinb         = (float*)alloc((size_t)S * 128 * 4);
    __hip_bfloat16* scores = (__hip_bfloat16*)alloc((size_t)NH * S * S * 2);
    __hip_bfloat16* probs  = (__hip_bfloat16*)alloc((size_t)NH * S * S * 2);

    const long SLq = 2048L * 2048, SLkv = 1024L * 2048, SLff = 8192L * 2048;
    const long nWlm = (long)VOCAB * D;
    __hip_bfloat16* wqkvb = (__hip_bfloat16*)alloc(4L * 4096 * 2048 * 2);
    __hip_bfloat16* wgub  = (__hip_bfloat16*)alloc(4L * 16384 * 2048 * 2); // interleaved wg/wu
    __hip_bfloat16* wob   = (__hip_bfloat16*)alloc(4L * SLq * 2);
    __hip_bfloat16* wdb   = (__hip_bfloat16*)alloc(4L * SLff * 2);
    __hip_bfloat16* wlmb  = (__hip_bfloat16*)alloc(nWlm * 2);
    const bool big = (off <= ws_size);
    (void)in_sizes; (void)n_in; (void)out_size;

    rope_table_kernel<<<dim3(S), dim3(128), 0, stream>>>(cosb, sinb);
    embed_kernel<<<dim3(D / 256, S), dim3(256), 0, stream>>>(ids, embedW, h);

    auto cvt = [&](const float* s, __hip_bfloat16* dp, long n) {
        long n8 = n / 8;
        long want = (n8 + 255) / 256;
        int blocks = (int)(want < 2048 ? want : 2048);
        cvt_bf16_kernel<<<dim3(blocks), dim3(256), 0, stream>>>(s, dp, n8);
    };
    auto cvtI = [&](const float* s, __hip_bfloat16* dp, int half, long n) {
        long n8 = n / 8;
        long want = (n8 + 255) / 256;
        int blocks = (int)(want < 2048 ? want : 2048);
        cvt_inter_kernel<<<dim3(blocks), dim3(256), 0, stream>>>(s, dp, half, n8);
    };

    // launchers: p256 = read-ahead 8-phase 256x256 (512 thr), p128 = 128x128 2-phase (256 thr)
    auto p256 = [&](int epi, const __hip_bfloat16* A, const __hip_bfloat16* B, void* C,
                    int K, int lda, int ldb, int ldc, int gx, int gy) {
        dim3 grid(gx * gy, 1, 1);
        if (epi == 3)
            gemm_8ph<3><<<grid, 512, 0, stream>>>(A, B, C, K, lda, ldb, ldc, gx);
        else
            gemm_8ph<5><<<grid, 512, 0, stream>>>(A, B, C, K, lda, ldb, ldc, gx);
    };
    auto p128 = [&](int epi, const __hip_bfloat16* A, const __hip_bfloat16* B, void* C,
                    int K, int lda, int ldb, int ldc, int gx, int gy, int gz,
                    long aB, long bB, long cB, int bzDiv, int kMode) {
        dim3 grid(gx * gy, 1, gz);
        switch (epi) {
        case 0: gemm_pipe<0, 2, 2, 4, 4><<<grid, 256, 0, stream>>>(A, B, C, K, lda, ldb, ldc, aB, bB, cB, bzDiv, gx, kMode); break;
        default: gemm_pipe<1, 2, 2, 4, 4><<<grid, 256, 0, stream>>>(A, B, C, K, lda, ldb, ldc, aB, bB, cB, bzDiv, gx, kMode); break;
        }
    };

    for (int l = 0; l < NLAYER; ++l) {
        int isLocal = (l % 2 == 0) ? 1 : 0;
        rms_bf16_kernel<<<dim3(S), dim3(256), 0, stream>>>(h, ln_in + l * D, xb);
        if (big) {
            // convert this layer's qkv weights just-in-time (L3-hot for the GEMM read)
            cvt(wq + l * SLq,  wqkvb + (size_t)l * 4096 * 2048,                SLq);
            cvt(wk + l * SLkv, wqkvb + (size_t)l * 4096 * 2048 + 2048L * 2048, SLkv);
            cvt(wv + l * SLkv, wqkvb + (size_t)l * 4096 * 2048 + 3072L * 2048, SLkv);
            p128(1, xb, wqkvb + (size_t)l * 4096 * 2048, qkvb, D, D, D, 4096, 16, 32, 1, 0, 0, 0, 1, 0);
        } else {
            gemm_f32w<1><<<dim3(16, 16), 256, 0, stream>>>(xb, wq + l * SLq, qkvb, D, D, D, 4096);
            gemm_f32w<1><<<dim3(16, 8), 256, 0, stream>>>(xb, wk + l * SLkv, qkvb + 2048, D, D, D, 4096);
            gemm_f32w<1><<<dim3(16, 8), 256, 0, stream>>>(xb, wv + l * SLkv, qkvb + 3072, D, D, D, 4096);
        }
        rope_kernel<<<dim3(S, NH), dim3(128), 0, stream>>>(qkvb, cosb, sinb, 4096);
        rope_kernel<<<dim3(S, NKV), dim3(128), 0, stream>>>(qkvb + 2048, cosb, sinb, 4096);
        transpose_v_kernel<<<dim3(S / 64, HD / 64, NKV), 256, 0, stream>>>(qkvb + 3072, vT, 4096);
        // scores = q @ k^T per head (bf16 out), masked-tile skip
        p128(1, qkvb, qkvb + 2048, scores, HD, 4096, 4096, S, 16, 16, NH,
             (long)HD, (long)HD, (long)S * S, 2, isLocal ? 2 : 1);
        softmax_kernel<<<dim3(S, NH), dim3(256), 0, stream>>>(scores, probs, isLocal);
        // a = probs @ vT, K-range restricted to valid band
        p128(1, probs, vT, ab, S, S, S, NH * HD, 16, 2, NH,
             (long)S * S, (long)HD * S, (long)HD, 2, isLocal ? 4 : 3);
        if (big) {
            cvt(wo + l * SLq, wob + (size_t)l * SLq, SLq);
            p128(0, ab, wob + (size_t)l * SLq, tmpf, NH * HD, NH * HD, NH * HD, D, 16, 16, 1, 0, 0, 0, 1, 0);
        } else {
            gemm_f32w<0><<<dim3(16, 16), 256, 0, stream>>>(ab, wo + l * SLq, tmpf, NH * HD, NH * HD, NH * HD, D);
        }
        resid_rms_kernel<<<dim3(S), dim3(256), 0, stream>>>(h, tmpf, ln_pa + l * D);
        rms_bf16_kernel<<<dim3(S), dim3(256), 0, stream>>>(h, ln_pf + l * D, xb);
        if (big) {
            cvtI(wg + l * SLff, wgub + (size_t)l * 16384 * 2048, 0, SLff);
            cvtI(wu + l * SLff, wgub + (size_t)l * 16384 * 2048, 1, SLff);
            // fused gate|up with interleaved rows; epilogue writes gelu(gate)*up -> guP [S][8192]
            p256(5, xb, wgub + (size_t)l * 16384 * 2048, guP, D, D, D, FF, 8, 64);
        } else {
            gemm_f32w<2><<<dim3(16, 64), 256, 0, stream>>>(xb, wg + l * SLff, gu, D, D, D, 16384);
            gemm_f32w<1><<<dim3(16, 64), 256, 0, stream>>>(xb, wu + l * SLff, gu + 8192, D, D, D, 16384);
            mul_gu_kernel<<<dim3((S * FF) / (256 * 8)), 256, 0, stream>>>(gu);
        }
        if (big) {
            cvt(wd + l * SLff, wdb + (size_t)l * SLff, SLff);
            p128(0, guP, wdb + (size_t)l * SLff, tmpf, FF, FF, FF, D, 16, 16, 1, 0, 0, 0, 1, 0);
        } else {
            gemm_f32w<0><<<dim3(16, 16), 256, 0, stream>>>(gu, wd + l * SLff, tmpf, FF, 16384, FF, D);
        }
        resid_rms_kernel<<<dim3(S), dim3(256), 0, stream>>>(h, tmpf, ln_pff + l * D);
    }

    rms_bf16_kernel<<<dim3(S), dim3(256), 0, stream>>>(h, ln_f, xb);
    if (big) {
        cvt(w_lm, wlmb, nWlm);
        p256(3, xb, wlmb, out, D, D, D, VOCAB, 8, VOCAB / 256);
    } else {
        gemm_f32w<3><<<dim3(16, VOCAB / 128), 256, 0, stream>>>(xb, w_lm, out, D, D, D, VOCAB);
    }
}